// Round 9
// baseline (5165.662 us; speedup 1.0000x reference)
//
#include <hip/hip_runtime.h>
#include <hip/hip_bf16.h>

typedef __hip_bfloat16 bf16;

constexpr int NN = 307, TT = 12, BB = 32, HH = 64, EE = 10, HEADS = 4, HD = 16, HORIZON = 12;

// ---------------- staged fp32 input offsets ----------------
constexpr int S_SRC = 0,       S_EMB = 117888,  S_GW0 = 120958,  S_GB0 = 287358,
              S_UW0 = 288638,  S_UB0 = 371838,  S_GW1 = 372478,  S_GB1 = 700158,
              S_UW1 = 701438,  S_UB1 = 865278,  S_MLW = 865918,  S_MLB = 865982,
              S_WQ  = 866046,  S_BQ  = 870142,  S_WK  = 870206,  S_BK  = 874302,
              S_WV  = 874366,  S_BV  = 878462,  S_WO  = 878526,  S_BO  = 882622,
              S_FW1 = 882686,  S_FB1 = 948222,  S_FW2 = 949246,  S_FB2 = 1014782,
              S_L1G = 1014846, S_L1B = 1014910, S_L2G = 1014974, S_L2B = 1015038,
              S_WS  = 1015102, S_WT  = 1034750, S_CW  = 1054398, S_CB  = 1055166;

// ---------------- fp32 work regions ----------------
constexpr size_t OFF_A    = 1055178;   // 307*307
constexpr size_t OFF_OUT0 = 1149427;   // [t][n][b][c] 12*307*2048
constexpr size_t OFF_H    = 8694259;   // [n][b][c] 307*2048
constexpr size_t OFF_ZH   = 9322995;
constexpr size_t OFF_R    = 9951731;
constexpr size_t OFF_AX0  = 11209203;  // [t][n][b] 12*307*32
constexpr size_t OFF_AX1  = 11327091;  // [t][n][b][c] 12*307*2048
constexpr size_t OFF_PE   = 18871923;  // 12*64
constexpr size_t OFF_OLN  = 18872691;
constexpr size_t OFF_O2   = 19501427;
constexpr size_t OFF_WB   = 20130164;  // fp32 reordered per-node GRU weights

// Reordered weight blocks (fp32; bf16 storage fails: scan amplifies to 0.19 absmax — r3)
constexpr size_t G0X = OFF_WB +        0;  // 307*2*128
constexpr size_t G0H = OFF_WB +    78592;  // 307*128*128
constexpr size_t BG0 = OFF_WB +  5108480;  // 307*128
constexpr size_t U0X = OFF_WB +  5147776;  // 307*2*64
constexpr size_t U0H = OFF_WB +  5187072;  // 307*128*64
constexpr size_t BU0 = OFF_WB +  7702016;  // 307*64
constexpr size_t G1X = OFF_WB +  7721664;  // 307*128*128
constexpr size_t G1H = OFF_WB + 12751552;  // 307*128*128
constexpr size_t BG1 = OFF_WB + 17781440;  // 307*128
constexpr size_t U1X = OFF_WB + 17820736;  // 307*128*64
constexpr size_t U1H = OFF_WB + 20335680;  // 307*128*64
constexpr size_t BU1 = OFF_WB + 22850624;  // 307*64
constexpr size_t OFF_GXP = OFF_WB + 22870272;       // [t][n][b][128] preact x-part (bias folded)
constexpr size_t OFF_UXP = OFF_GXP + 15089664;      // [t][n][b][64]
constexpr size_t G_TOTAL = OFF_UXP + 7544832 + 4096;

// r8->r9: serial fused kernels split by batch half (614 blocks, 2.4/CU) — r8's 307
// blocks gave 1.2/CU and a 1.67x imbalance wall (51 CUs ran 2 sequential blocks).
// xprep grids swapped to t-fastest so per-n weight slices stay cache-hot (r8 FETCH 209MB).

__device__ float g_buf[G_TOTAL];
__device__ int g_flag;   // 1 = inputs are bf16, 0 = fp32

__device__ __forceinline__ float wave_sum(float v) {
    #pragma unroll
    for (int off = 32; off > 0; off >>= 1) v += __shfl_xor(v, off, 64);
    return v;
}

// ---------------- dtype detection ----------------
__global__ void k_detect(const void* emb_raw) {
    const bf16* p = (const bf16*)emb_raw;
    int lane = threadIdx.x;
    float v = __bfloat162float(p[lane]);
    bool plaus = (v == v) && (fabsf(v) <= 1e4f) && (v == 0.f || fabsf(v) >= 1e-4f);
    float c = wave_sum(plaus ? 1.f : 0.f);
    if (lane == 0) g_flag = (c >= 52.f) ? 1 : 0;
}

// ---------------- ingest all inputs as fp32 ----------------
struct PtrPack { const void* p[32]; };
__device__ const int D_CNT[32] = {117888,3070,166400,1280,83200,640,327680,1280,163840,640,
                                  64,64,4096,64,4096,64,4096,64,4096,64,
                                  65536,1024,65536,64,64,64,64,64,19648,19648,768,12};
__device__ const int D_OFF[32] = {S_SRC,S_EMB,S_GW0,S_GB0,S_UW0,S_UB0,S_GW1,S_GB1,S_UW1,S_UB1,
                                  S_MLW,S_MLB,S_WQ,S_BQ,S_WK,S_BK,S_WV,S_BV,S_WO,S_BO,
                                  S_FW1,S_FB1,S_FW2,S_FB2,S_L1G,S_L1B,S_L2G,S_L2B,S_WS,S_WT,S_CW,S_CB};
__device__ const int D_CHK[33] = {0,461,473,1123,1128,1453,1456,2736,2741,3381,3384,3385,3386,
                                  3402,3403,3419,3420,3436,3437,3453,3454,3710,3714,3970,3971,
                                  3972,3973,3974,3975,4052,4129,4132,4133};

__global__ void k_ingest(PtrPack pk) {
    int bid = blockIdx.x;
    int s = 0;
    while (s < 31 && bid >= D_CHK[s + 1]) s++;
    int i = (bid - D_CHK[s]) * 256 + threadIdx.x;
    if (i >= D_CNT[s]) return;
    float v;
    if (g_flag) v = __bfloat162float(((const bf16*)pk.p[s])[i]);
    else        v = ((const float*)pk.p[s])[i];
    g_buf[(size_t)D_OFF[s] + i] = v;
}

// ---------------- adjacency ----------------
__global__ void k_adj() {
    int n = blockIdx.x;
    int tid = threadIdx.x;            // 512
    __shared__ float en[EE];
    __shared__ float red[512];
    if (tid < EE) en[tid] = g_buf[S_EMB + n * EE + tid];
    __syncthreads();
    bool act = tid < NN;
    float d = 0.f;
    if (act) {
        #pragma unroll
        for (int e = 0; e < EE; e++) d += en[e] * g_buf[S_EMB + tid * EE + e];
        d = fmaxf(d, 0.f);
    }
    red[tid] = act ? d : -1e30f;
    __syncthreads();
    for (int s = 256; s > 0; s >>= 1) { if (tid < s) red[tid] = fmaxf(red[tid], red[tid + s]); __syncthreads(); }
    float mx = red[0];
    __syncthreads();
    float ex = act ? expf(d - mx) : 0.f;
    red[tid] = ex;
    __syncthreads();
    for (int s = 256; s > 0; s >>= 1) { if (tid < s) red[tid] += red[tid + s]; __syncthreads(); }
    float inv = 1.f / red[0];
    if (act) g_buf[OFF_A + (size_t)n * NN + tid] = ex * inv;
}

// ---------------- per-node GRU weights -> fp32, reordered into Wx/Wh blocks ----------------
__device__ const unsigned SEGC[9] = {0u,5108480u,5147776u,7702016u,7721664u,17781440u,17820736u,22850624u,22870272u};
__device__ const int SEGJ[8]      = {16640,128,8320,64,32768,128,16384,64};
__device__ const int SEGS[8]      = {S_GW0,S_GB0,S_UW0,S_UB0,S_GW1,S_GB1,S_UW1,S_UB1};

__global__ void k_nodew_all() {
    unsigned idx = blockIdx.x * 256u + threadIdx.x;
    if (idx >= 22870272u) return;
    int s = 0;
    while (s < 7 && idx >= SEGC[s + 1]) s++;
    unsigned rem = idx - SEGC[s];
    unsigned J = (unsigned)SEGJ[s];
    unsigned n = rem / J;
    unsigned j = rem - n * J;
    float acc = 0.f;
    const float* eb = g_buf + S_EMB + n * EE;
    const float* w  = g_buf + SEGS[s];
    #pragma unroll
    for (int e = 0; e < EE; e++) acc += eb[e] * w[(size_t)e * J + j];
    size_t dst;
    if (s == 0) {        // gw0: j = (k*65+i)*128+o
        unsigned o = j & 127, kk = j >> 7, k = kk / 65, i = kk % 65;
        dst = (i == 0) ? G0X + ((size_t)n * 2 + k) * 128 + o
                       : G0H + ((size_t)n * 128 + k * 64 + (i - 1)) * 128 + o;
    } else if (s == 1) { dst = BG0 + (size_t)n * 128 + j;
    } else if (s == 2) { // uw0: j = (k*65+i)*64+o
        unsigned o = j & 63, kk = j >> 6, k = kk / 65, i = kk % 65;
        dst = (i == 0) ? U0X + ((size_t)n * 2 + k) * 64 + o
                       : U0H + ((size_t)n * 128 + k * 64 + (i - 1)) * 64 + o;
    } else if (s == 3) { dst = BU0 + (size_t)n * 64 + j;
    } else if (s == 4) { // gw1: j = (k*128+i)*128+o
        unsigned o = j & 127, kk = j >> 7, k = kk >> 7, i = kk & 127;
        dst = (i < 64) ? G1X + ((size_t)n * 128 + k * 64 + i) * 128 + o
                       : G1H + ((size_t)n * 128 + k * 64 + (i - 64)) * 128 + o;
    } else if (s == 5) { dst = BG1 + (size_t)n * 128 + j;
    } else if (s == 6) { // uw1: j = (k*128+i)*64+o
        unsigned o = j & 63, kk = j >> 6, k = kk >> 7, i = kk & 127;
        dst = (i < 64) ? U1X + ((size_t)n * 128 + k * 64 + i) * 64 + o
                       : U1H + ((size_t)n * 128 + k * 64 + (i - 64)) * 64 + o;
    } else {             dst = BU1 + (size_t)n * 64 + j; }
    g_buf[dst] = acc;
}

// ---------------- positional embedding ----------------
__global__ void k_pe() {
    int tid = threadIdx.x;            // 768
    int t = tid >> 6, h = tid & 63;
    float ex = (float)(h & ~1) / 64.f;
    float ang = (float)t * powf(10000.f, -ex);
    g_buf[OFF_PE + tid] = (h & 1) ? cosf(ang) : sinf(ang);
}

__global__ void k_zero(size_t off, int cnt) {
    int i = blockIdx.x * 256 + threadIdx.x;
    if (i < cnt) g_buf[off + i] = 0.f;
}

// ---------------- AX0[t][n][b] = sum_m A[n,m] * src[b,t,m] ----------------
__global__ __launch_bounds__(256) void k_ax0() {
    int t = blockIdx.y;
    int n0 = blockIdx.x * 8;
    int b = threadIdx.x & 31, nl = threadIdx.x >> 5;
    __shared__ float As[8][68];
    __shared__ float xs[32][65];
    float acc = 0.f;
    for (int m0 = 0; m0 < NN; m0 += 64) {
        int jend = min(64, NN - m0);
        for (int idx = threadIdx.x; idx < 8 * 64; idx += 256) {
            int i = idx >> 6, jj = idx & 63;
            int n = n0 + i, m = m0 + jj;
            As[i][jj] = (n < NN && m < NN) ? g_buf[OFF_A + (size_t)n * NN + m] : 0.f;
        }
        for (int idx = threadIdx.x; idx < 32 * 64; idx += 256) {
            int bb = idx >> 6, jj = idx & 63;
            int m = m0 + jj;
            xs[bb][jj] = (m < NN) ? g_buf[S_SRC + ((size_t)bb * TT + t) * NN + m] : 0.f;
        }
        __syncthreads();
        for (int jj = 0; jj < jend; jj++) acc += As[nl][jj] * xs[b][jj];
        __syncthreads();
    }
    int n = n0 + nl;
    if (n < NN) g_buf[OFF_AX0 + ((size_t)t * NN + n) * 32 + b] = acc;
}

// ---------------- standalone agg GEMM (used for AX1, z=12 parallel) ----------------
__global__ __launch_bounds__(256) void k_aggmat(size_t srcOff, size_t dstOff, size_t srcTS, size_t dstTS) {
    int z = blockIdx.z;
    const float* __restrict__ srcp = g_buf + srcOff + (size_t)z * srcTS;
    float* __restrict__ dstp = g_buf + dstOff + (size_t)z * dstTS;
    int n0 = blockIdx.x * 64;
    int col0 = blockIdx.y * 64;
    int tid = threadIdx.x;
    int tn = tid >> 4, tc = tid & 15;
    __shared__ float As[32][68];
    __shared__ float Xs[32][64];
    float acc[4][4];
    #pragma unroll
    for (int i = 0; i < 4; i++)
        #pragma unroll
        for (int j = 0; j < 4; j++) acc[i][j] = 0.f;
    for (int k0 = 0; k0 < NN; k0 += 32) {
        for (int idx = tid; idx < 64 * 32; idx += 256) {
            int k = idx & 31, i = idx >> 5;
            int n = n0 + i, m = k0 + k;
            As[k][i] = (n < NN && m < NN) ? g_buf[OFF_A + (size_t)n * NN + m] : 0.f;
        }
        for (int idx = tid; idx < 32 * 64; idx += 256) {
            int c = idx & 63, k = idx >> 6;
            int m = k0 + k;
            Xs[k][c] = (m < NN) ? srcp[(size_t)m * 2048 + col0 + c] : 0.f;
        }
        __syncthreads();
        #pragma unroll
        for (int k = 0; k < 32; k++) {
            float4 a4 = *(const float4*)&As[k][tn * 4];
            float4 x4 = *(const float4*)&Xs[k][tc * 4];
            const float* aa = (const float*)&a4;
            const float* xx = (const float*)&x4;
            #pragma unroll
            for (int i = 0; i < 4; i++)
                #pragma unroll
                for (int j = 0; j < 4; j++) acc[i][j] += aa[i] * xx[j];
        }
        __syncthreads();
    }
    #pragma unroll
    for (int i = 0; i < 4; i++) {
        int n = n0 + tn * 4 + i;
        if (n < NN) {
            float4 v = make_float4(acc[i][0], acc[i][1], acc[i][2], acc[i][3]);
            *(float4*)&dstp[(size_t)n * 2048 + col0 + tc * 4] = v;
        }
    }
}

// ---------------- x-part preact precompute, layer 0 (K=2); grid (12, NN) t-fastest ----------------
__global__ __launch_bounds__(256) void k_xprep0() {
    int t = blockIdx.x, n = blockIdx.y, tid = threadIdx.x;
    __shared__ float xv[32], ax[32];
    if (tid < 32) {
        xv[tid] = g_buf[S_SRC + ((size_t)tid * TT + t) * NN + n];
        ax[tid] = g_buf[OFF_AX0 + ((size_t)t * NN + n) * 32 + tid];
    }
    __syncthreads();
    size_t pbase = ((size_t)t * NN + n) * 32;
    for (int idx = tid; idx < 4096; idx += 256) {
        int b = idx >> 7, o = idx & 127;
        g_buf[OFF_GXP + (pbase + b) * 128 + o] =
            g_buf[BG0 + (size_t)n * 128 + o]
          + g_buf[G0X + ((size_t)n * 2 + 0) * 128 + o] * xv[b]
          + g_buf[G0X + ((size_t)n * 2 + 1) * 128 + o] * ax[b];
    }
    for (int idx = tid; idx < 2048; idx += 256) {
        int b = idx >> 6, o = idx & 63;
        g_buf[OFF_UXP + (pbase + b) * 64 + o] =
            g_buf[BU0 + (size_t)n * 64 + o]
          + g_buf[U0X + ((size_t)n * 2 + 0) * 64 + o] * xv[b]
          + g_buf[U0X + ((size_t)n * 2 + 1) * 64 + o] * ax[b];
    }
}

// ---------------- x-part preact precompute, layer 1 (K=128); grid (12, NN) t-fastest ----------------
__global__ __launch_bounds__(256, 2) void k_xprep1() {
    __shared__ float smem[12544];
    float* xh = smem;            // [32][136]
    float* Wl = smem + 4352;     // [64][128]
    int t = blockIdx.x, n = blockIdx.y, tid = threadIdx.x;
    size_t pbase = ((size_t)t * NN + n) * 32;
    for (int idx = tid; idx < 4096; idx += 256) {
        int bl = idx >> 7, c = idx & 127;
        float v = (c < 64) ? g_buf[OFF_OUT0 + (pbase + bl) * 64 + c]
                           : g_buf[OFF_AX1 + (pbase + bl) * 64 + (c - 64)];
        xh[bl * 136 + c] = v;
    }
    int o = tid & 63, bl0 = (tid >> 6) * 8;
    float accz[8], accr[8];
    #pragma unroll
    for (int j = 0; j < 8; j++) {
        accz[j] = g_buf[BG1 + (size_t)n * 128 + o];
        accr[j] = g_buf[BG1 + (size_t)n * 128 + o + 64];
    }
    for (int ch = 0; ch < 2; ch++) {
        __syncthreads();
        const float4* wsrc = (const float4*)&g_buf[G1X + (size_t)n * 16384 + ch * 8192];
        float4* wdst = (float4*)Wl;
        for (int idx = tid; idx < 2048; idx += 256) wdst[idx] = wsrc[idx];
        __syncthreads();
        #pragma unroll 4
        for (int kq = 0; kq < 64; kq += 4) {
            float4 xv[8];
            #pragma unroll
            for (int j = 0; j < 8; j++) xv[j] = *(const float4*)&xh[(bl0 + j) * 136 + ch * 64 + kq];
            #pragma unroll
            for (int q = 0; q < 4; q++) {
                float w0 = Wl[(kq + q) * 128 + o];
                float w1 = Wl[(kq + q) * 128 + o + 64];
                #pragma unroll
                for (int j = 0; j < 8; j++) {
                    float xx = ((const float*)&xv[j])[q];
                    accz[j] += xx * w0;
                    accr[j] += xx * w1;
                }
            }
        }
    }
    #pragma unroll
    for (int j = 0; j < 8; j++) {
        g_buf[OFF_GXP + (pbase + bl0 + j) * 128 + o]      = accz[j];
        g_buf[OFF_GXP + (pbase + bl0 + j) * 128 + o + 64] = accr[j];
    }
    float acc[8];
    #pragma unroll
    for (int j = 0; j < 8; j++) acc[j] = g_buf[BU1 + (size_t)n * 64 + o];
    for (int ch = 0; ch < 2; ch++) {
        __syncthreads();
        const float4* wsrc = (const float4*)&g_buf[U1X + (size_t)n * 8192 + ch * 4096];
        float4* wdst = (float4*)Wl;
        for (int idx = tid; idx < 1024; idx += 256) wdst[idx] = wsrc[idx];
        __syncthreads();
        #pragma unroll 4
        for (int kq = 0; kq < 64; kq += 4) {
            float4 xv[8];
            #pragma unroll
            for (int j = 0; j < 8; j++) xv[j] = *(const float4*)&xh[(bl0 + j) * 136 + ch * 64 + kq];
            #pragma unroll
            for (int q = 0; q < 4; q++) {
                float w = Wl[(kq + q) * 64 + o];
                #pragma unroll
                for (int j = 0; j < 8; j++) acc[j] += ((const float*)&xv[j])[q] * w;
            }
        }
    }
    #pragma unroll
    for (int j = 0; j < 8; j++) g_buf[OFF_UXP + (pbase + bl0 + j) * 64 + o] = acc[j];
}

// ---------------- fused gate, batch-half split: own-agg + h-part GEMM + sigmoid ----------------
// grid (2, NN): blockIdx.x = batch half, blockIdx.y = node.
template<int L>
__global__ __launch_bounds__(256) void k_gateF(int t) {
    constexpr size_t GH = (L == 0) ? G0H : G1H;
    int bh = blockIdx.x, n = blockIdx.y, tid = threadIdx.x;
    __shared__ float Arow[308];
    __shared__ float xh[16 * 136];   // [b-local][k]: k<64 = h, k>=64 = A@h
    __shared__ float Wl[64 * 128];
    for (int idx = tid; idx < NN; idx += 256) Arow[idx] = g_buf[OFF_A + (size_t)n * NN + idx];
    for (int idx = tid; idx < 1024; idx += 256) {
        int bl = idx >> 6, c = idx & 63;
        xh[bl * 136 + c] = g_buf[OFF_H + (size_t)n * 2048 + (size_t)(bh * 16 + bl) * 64 + c];
    }
    __syncthreads();
    // own aggregation: this block's 1024-float (16b x 64c) slice of A[n,:] @ H
    float ag0 = 0.f, ag1 = 0.f, ag2 = 0.f, ag3 = 0.f;
    #pragma unroll 4
    for (int m = 0; m < NN; m++) {
        float a = Arow[m];
        float4 h0 = *(const float4*)&g_buf[OFF_H + (size_t)m * 2048 + bh * 1024 + tid * 4];
        ag0 += a * h0.x; ag1 += a * h0.y; ag2 += a * h0.z; ag3 += a * h0.w;
    }
    {
        int flat = tid * 4;
        int bl = flat >> 6, c = flat & 63;
        float* dst = &xh[bl * 136 + 64 + c];
        dst[0] = ag0; dst[1] = ag1; dst[2] = ag2; dst[3] = ag3;
    }
    int o = tid & 63, bl0 = (tid >> 6) * 4;   // 4 local batches per subgroup
    size_t pbase = ((size_t)t * NN + n) * 32 + bh * 16;
    float accz[4], accr[4];
    #pragma unroll
    for (int j = 0; j < 4; j++) {
        accz[j] = g_buf[OFF_GXP + (pbase + bl0 + j) * 128 + o];
        accr[j] = g_buf[OFF_GXP + (pbase + bl0 + j) * 128 + o + 64];
    }
    for (int ch = 0; ch < 2; ch++) {
        __syncthreads();
        const float4* wsrc = (const float4*)&g_buf[GH + (size_t)n * 16384 + ch * 8192];
        float4* wdst = (float4*)Wl;
        for (int idx = tid; idx < 2048; idx += 256) wdst[idx] = wsrc[idx];
        __syncthreads();
        #pragma unroll 4
        for (int kq = 0; kq < 64; kq += 4) {
            float4 xv[4];
            #pragma unroll
            for (int j = 0; j < 4; j++) xv[j] = *(const float4*)&xh[(bl0 + j) * 136 + ch * 64 + kq];
            #pragma unroll
            for (int q = 0; q < 4; q++) {
                float w0 = Wl[(kq + q) * 128 + o];
                float w1 = Wl[(kq + q) * 128 + o + 64];
                #pragma unroll
                for (int j = 0; j < 4; j++) {
                    float xx = ((const float*)&xv[j])[q];
                    accz[j] += xx * w0;
                    accr[j] += xx * w1;
                }
            }
        }
    }
    #pragma unroll
    for (int j = 0; j < 4; j++) {
        int bl = bl0 + j;
        int b = bh * 16 + bl;
        float z = 1.f / (1.f + expf(-accz[j]));
        float r = 1.f / (1.f + expf(-accr[j]));
        float hv = xh[bl * 136 + o];
        g_buf[OFF_ZH + (size_t)n * 2048 + (size_t)b * 64 + o] = z * hv;
        g_buf[OFF_R  + (size_t)n * 2048 + (size_t)b * 64 + o] = r;
    }
}

// ---------------- fused update, batch-half split ----------------
template<int L, bool WOUT>
__global__ __launch_bounds__(256) void k_updF(int t) {
    constexpr size_t UH = (L == 0) ? U0H : U1H;
    int bh = blockIdx.x, n = blockIdx.y, tid = threadIdx.x;
    __shared__ float Arow[308];
    __shared__ float xh[16 * 136];   // [b-local][k]: k<64 = z*h, k>=64 = A@(z*h)
    __shared__ float Wl[64 * 64];
    for (int idx = tid; idx < NN; idx += 256) Arow[idx] = g_buf[OFF_A + (size_t)n * NN + idx];
    for (int idx = tid; idx < 1024; idx += 256) {
        int bl = idx >> 6, c = idx & 63;
        xh[bl * 136 + c] = g_buf[OFF_ZH + (size_t)n * 2048 + (size_t)(bh * 16 + bl) * 64 + c];
    }
    __syncthreads();
    float ag0 = 0.f, ag1 = 0.f, ag2 = 0.f, ag3 = 0.f;
    #pragma unroll 4
    for (int m = 0; m < NN; m++) {
        float a = Arow[m];
        float4 h0 = *(const float4*)&g_buf[OFF_ZH + (size_t)m * 2048 + bh * 1024 + tid * 4];
        ag0 += a * h0.x; ag1 += a * h0.y; ag2 += a * h0.z; ag3 += a * h0.w;
    }
    {
        int flat = tid * 4;
        int bl = flat >> 6, c = flat & 63;
        float* dst = &xh[bl * 136 + 64 + c];
        dst[0] = ag0; dst[1] = ag1; dst[2] = ag2; dst[3] = ag3;
    }
    int o = tid & 63, bl0 = (tid >> 6) * 4;
    size_t pbase = ((size_t)t * NN + n) * 32 + bh * 16;
    float acc[4];
    #pragma unroll
    for (int j = 0; j < 4; j++) acc[j] = g_buf[OFF_UXP + (pbase + bl0 + j) * 64 + o];
    for (int ch = 0; ch < 2; ch++) {
        __syncthreads();
        const float4* wsrc = (const float4*)&g_buf[UH + (size_t)n * 8192 + ch * 4096];
        float4* wdst = (float4*)Wl;
        for (int idx = tid; idx < 1024; idx += 256) wdst[idx] = wsrc[idx];
        __syncthreads();
        #pragma unroll 4
        for (int kq = 0; kq < 64; kq += 4) {
            float4 xv[4];
            #pragma unroll
            for (int j = 0; j < 4; j++) xv[j] = *(const float4*)&xh[(bl0 + j) * 136 + ch * 64 + kq];
            #pragma unroll
            for (int q = 0; q < 4; q++) {
                float w = Wl[(kq + q) * 64 + o];
                #pragma unroll
                for (int j = 0; j < 4; j++) acc[j] += ((const float*)&xv[j])[q] * w;
            }
        }
    }
    #pragma unroll
    for (int j = 0; j < 4; j++) {
        int b = bh * 16 + bl0 + j;
        size_t base = (size_t)n * 2048 + (size_t)b * 64 + o;
        float hc = tanhf(acc[j]);
        float r = g_buf[OFF_R + base];
        float hold = g_buf[OFF_H + base];
        float hn = r * hold + (1.f - r) * hc;
        g_buf[OFF_H + base] = hn;
        if constexpr (WOUT) g_buf[OFF_OUT0 + (pbase + bl0 + j) * 64 + o] = hn;
    }
}

// ---------------- fused attention (t=T-1 only) + LN1; 4 (b,n) per block ----------------
__global__ __launch_bounds__(256) void k_attn() {
    int wid = threadIdx.x >> 6;
    int lane = threadIdx.x & 63;
    int g = blockIdx.x * 4 + wid;
    int b = g / NN, n = g - b * NN;
    __shared__ float x[4][TT][HH], kk[4][TT][HH], vv[4][TT][HH];
    __shared__ float q[4][HH], o1[4][HH], sc[4][HEADS][TT], aw[4][HEADS][TT];
    float mw = g_buf[S_MLW + lane];
    float mb = g_buf[S_MLB + lane];
    #pragma unroll
    for (int tt = 0; tt < TT; tt++) {
        float s = g_buf[S_SRC + ((size_t)b * TT + tt) * NN + n];
        x[wid][tt][lane] = s * mw + mb + g_buf[OFF_PE + tt * HH + lane];
    }
    __syncthreads();
    float ka[TT], va[TT];
    #pragma unroll
    for (int tt = 0; tt < TT; tt++) { ka[tt] = g_buf[S_BK + lane]; va[tt] = g_buf[S_BV + lane]; }
    float qa = g_buf[S_BQ + lane];
    for (int i = 0; i < HH; i++) {
        float wkv = g_buf[S_WK + i * HH + lane];
        float wvv = g_buf[S_WV + i * HH + lane];
        qa += x[wid][TT - 1][i] * g_buf[S_WQ + i * HH + lane];
        #pragma unroll
        for (int tt = 0; tt < TT; tt++) {
            float xv = x[wid][tt][i];
            ka[tt] += xv * wkv;
            va[tt] += xv * wvv;
        }
    }
    #pragma unroll
    for (int tt = 0; tt < TT; tt++) { kk[wid][tt][lane] = ka[tt]; vv[wid][tt][lane] = va[tt]; }
    q[wid][lane] = qa;
    __syncthreads();
    if (lane < HEADS * TT) {
        int head = lane / TT, ts = lane - head * TT;
        float s = 0.f;
        #pragma unroll
        for (int d = 0; d < HD; d++) s += q[wid][head * HD + d] * kk[wid][ts][head * HD + d];
        sc[wid][head][ts] = s * 0.25f;
    }
    __syncthreads();
    if (lane < HEADS * TT) {
        int head = lane / TT, ts = lane - head * TT;
        float mx = -1e30f;
        #pragma unroll
        for (int j = 0; j < TT; j++) mx = fmaxf(mx, sc[wid][head][j]);
        float sm = 0.f;
        #pragma unroll
        for (int j = 0; j < TT; j++) sm += expf(sc[wid][head][j] - mx);
        aw[wid][head][ts] = expf(sc[wid][head][ts] - mx) / sm;
    }
    __syncthreads();
    int head = lane >> 4;
    float oa = 0.f;
    #pragma unroll
    for (int tt = 0; tt < TT; tt++) oa += aw[wid][head][tt] * vv[wid][tt][lane];
    o1[wid][lane] = oa;
    __syncthreads();
    float acc = g_buf[S_BO + lane];
    for (int i = 0; i < HH; i++) acc += o1[wid][i] * g_buf[S_WO + i * HH + lane];
    float res = x[wid][TT - 1][lane] + acc;
    float mean = wave_sum(res) * (1.f / 64.f);
    float dv = res - mean;
    float var = wave_sum(dv * dv) * (1.f / 64.f);
    float ln = dv * rsqrtf(var + 1e-5f) * g_buf[S_L1G + lane] + g_buf[S_L1B + lane];
    g_buf[OFF_OLN + ((size_t)b * NN + n) * HH + lane] = ln;
}

// ---------------- FFN + LN2; 8 tokens per block ----------------
__global__ __launch_bounds__(256) void k_ffn() {
    int tok0 = blockIdx.x * 8;
    int tid = threadIdx.x;
    __shared__ float ox[8][HH];
    __shared__ float hid[8][1024];
    for (int idx = tid; idx < 8 * HH; idx += 256) {
        int tk = idx >> 6, hh = idx & 63;
        ox[tk][hh] = g_buf[OFF_OLN + (size_t)(tok0 + tk) * HH + hh];
    }
    __syncthreads();
    #pragma unroll
    for (int p = 0; p < 4; p++) {
        int j = tid + 256 * p;
        float bj = g_buf[S_FB1 + j];
        float a[8];
        #pragma unroll
        for (int tk = 0; tk < 8; tk++) a[tk] = bj;
        for (int i = 0; i < HH; i++) {
            float w = g_buf[S_FW1 + (size_t)i * 1024 + j];
            #pragma unroll
            for (int tk = 0; tk < 8; tk++) a[tk] += ox[tk][i] * w;
        }
        #pragma unroll
        for (int tk = 0; tk < 8; tk++) hid[tk][j] = fmaxf(a[tk], 0.f);
    }
    __syncthreads();
    int tk = tid >> 6, hh = tid & 63;
    float acc0 = g_buf[S_FB2 + hh], acc1 = acc0;
    for (int j = 0; j < 1024; j++) {
        float w = g_buf[S_FW2 + (size_t)j * HH + hh];
        acc0 += hid[tk][j] * w;
        acc1 += hid[tk + 4][j] * w;
    }
    #pragma unroll
    for (int ph = 0; ph < 2; ph++) {
        int tkk = tk + 4 * ph;
        float res = ox[tkk][hh] + (ph ? acc1 : acc0);
        float mean = wave_sum(res) * (1.f / 64.f);
        float dv = res - mean;
        float var = wave_sum(dv * dv) * (1.f / 64.f);
        float ln = dv * rsqrtf(var + 1e-5f) * g_buf[S_L2G + hh] + g_buf[S_L2B + hh];
        g_buf[OFF_O2 + (size_t)(tok0 + tkk) * HH + hh] = ln;
    }
}

// ---------------- final combine + horizon conv ----------------
__global__ void k_final(void* out) {
    int n = blockIdx.x, b = blockIdx.y;
    int h = threadIdx.x;
    __shared__ float comb[HH];
    comb[h] = g_buf[OFF_H + ((size_t)n * 32 + b) * 64 + h] * g_buf[S_WS + n * HH + h]
            + g_buf[OFF_O2 + ((size_t)b * NN + n) * 64 + h] * g_buf[S_WT + n * HH + h];
    __syncthreads();
    if (h < HORIZON) {
        float acc = g_buf[S_CB + h];
        #pragma unroll
        for (int i = 0; i < HH; i++) acc += comb[i] * g_buf[S_CW + h * HH + i];
        size_t oi = ((size_t)b * HORIZON + h) * NN + n;
        if (g_flag) ((bf16*)out)[oi] = __float2bfloat16(acc);
        else        ((float*)out)[oi] = acc;
    }
}

extern "C" void kernel_launch(void* const* d_in, const int* in_sizes, int n_in,
                              void* d_out, int out_size, void* d_ws, size_t ws_size,
                              hipStream_t stream) {
    PtrPack pk;
    for (int i = 0; i < 32; i++) pk.p[i] = d_in[i];

    k_detect<<<1, 64, 0, stream>>>(d_in[1]);
    k_ingest<<<4133, 256, 0, stream>>>(pk);
    k_adj<<<NN, 512, 0, stream>>>();
    k_nodew_all<<<89337, 256, 0, stream>>>();
    k_pe<<<1, 768, 0, stream>>>();
    k_ax0<<<dim3(39, 12), 256, 0, stream>>>();
    k_xprep0<<<dim3(12, NN), 256, 0, stream>>>();

    // ---- GRU layer 0: 2 fused dispatches per step (614 blocks each) ----
    k_zero<<<2456, 256, 0, stream>>>(OFF_H, 628736);
    for (int t = 0; t < TT; t++) {
        k_gateF<0><<<dim3(2, NN), 256, 0, stream>>>(t);
        k_updF<0, true><<<dim3(2, NN), 256, 0, stream>>>(t);
    }
    // ---- layer-1 x-part precompute (t-parallel) ----
    k_aggmat<<<dim3(5, 32, 12), 256, 0, stream>>>(OFF_OUT0, OFF_AX1, 628736, 628736);
    k_xprep1<<<dim3(12, NN), 256, 0, stream>>>();
    // ---- GRU layer 1 ----
    k_zero<<<2456, 256, 0, stream>>>(OFF_H, 628736);
    for (int t = 0; t < TT; t++) {
        k_gateF<1><<<dim3(2, NN), 256, 0, stream>>>(t);
        k_updF<1, false><<<dim3(2, NN), 256, 0, stream>>>(t);
    }
    // ---- transformer branch ----
    k_attn<<<2456, 256, 0, stream>>>();
    k_ffn<<<1228, 256, 0, stream>>>();
    // ---- combine + conv ----
    k_final<<<dim3(NN, BB), 64, 0, stream>>>(d_out);
}

// Round 10
// 3345.470 us; speedup vs baseline: 1.5441x; 1.5441x over previous
//
#include <hip/hip_runtime.h>
#include <hip/hip_bf16.h>

typedef __hip_bfloat16 bf16;

constexpr int NN = 307, TT = 12, BB = 32, HH = 64, EE = 10, HEADS = 4, HD = 16, HORIZON = 12;

// ---------------- staged fp32 input offsets ----------------
constexpr int S_SRC = 0,       S_EMB = 117888,  S_GW0 = 120958,  S_GB0 = 287358,
              S_UW0 = 288638,  S_UB0 = 371838,  S_GW1 = 372478,  S_GB1 = 700158,
              S_UW1 = 701438,  S_UB1 = 865278,  S_MLW = 865918,  S_MLB = 865982,
              S_WQ  = 866046,  S_BQ  = 870142,  S_WK  = 870206,  S_BK  = 874302,
              S_WV  = 874366,  S_BV  = 878462,  S_WO  = 878526,  S_BO  = 882622,
              S_FW1 = 882686,  S_FB1 = 948222,  S_FW2 = 949246,  S_FB2 = 1014782,
              S_L1G = 1014846, S_L1B = 1014910, S_L2G = 1014974, S_L2B = 1015038,
              S_WS  = 1015102, S_WT  = 1034750, S_CW  = 1054398, S_CB  = 1055166;

// ---------------- fp32 work regions ----------------
constexpr size_t OFF_A    = 1055178;   // 307*307
constexpr size_t OFF_OUT0 = 1149427;   // [t][n][b][c] 12*307*2048
constexpr size_t OFF_H    = 8694259;   // [n][b][c] 307*2048
constexpr size_t OFF_ZH   = 9322995;
constexpr size_t OFF_R    = 9951731;
constexpr size_t OFF_AX0  = 11209203;  // [t][n][b] 12*307*32
constexpr size_t OFF_AX1  = 11327091;  // [t][n][b][c] 12*307*2048
constexpr size_t OFF_PE   = 18871923;  // 12*64
constexpr size_t OFF_OLN  = 18872691;
constexpr size_t OFF_O2   = 19501427;
constexpr size_t OFF_WB   = 20130164;  // fp32 reordered per-node GRU weights

// Reordered weight blocks (fp32; bf16 storage fails: scan amplifies to 0.19 absmax — r3)
constexpr size_t G0X = OFF_WB +        0;  // 307*2*128
constexpr size_t G0H = OFF_WB +    78592;  // 307*128*128
constexpr size_t BG0 = OFF_WB +  5108480;  // 307*128
constexpr size_t U0X = OFF_WB +  5147776;  // 307*2*64
constexpr size_t U0H = OFF_WB +  5187072;  // 307*128*64
constexpr size_t BU0 = OFF_WB +  7702016;  // 307*64
constexpr size_t G1X = OFF_WB +  7721664;  // 307*128*128
constexpr size_t G1H = OFF_WB + 12751552;  // 307*128*128
constexpr size_t BG1 = OFF_WB + 17781440;  // 307*128
constexpr size_t U1X = OFF_WB + 17820736;  // 307*128*64
constexpr size_t U1H = OFF_WB + 20335680;  // 307*128*64
constexpr size_t BU1 = OFF_WB + 22850624;  // 307*64
constexpr size_t OFF_GXP = OFF_WB + 22870272;       // [t][n][b][128] preact x-part (bias folded)
constexpr size_t OFF_UXP = OFF_GXP + 15089664;      // [t][n][b][64]
constexpr size_t G_TOTAL = OFF_UXP + 7544832 + 4096;

// r9->r10: batch-half split REVERTED — it kept agg traffic identical (772MB either
// way: 307x2.5MB vs 614x1.26MB) and doubled weight fetch (54->88MB) -> regression.
// This round: r8 structure + depth-8 explicit prefetch in the agg loop (the agg is
// L3-LATENCY-bound, ~8 outstanding loads at unroll-4; 16 outstanding approaches the
// 18us/CU BW floor) + t==0 fast path (H=0: skip agg+Wh GEMM entirely).

__device__ float g_buf[G_TOTAL];
__device__ int g_flag;   // 1 = inputs are bf16, 0 = fp32

__device__ __forceinline__ float wave_sum(float v) {
    #pragma unroll
    for (int off = 32; off > 0; off >>= 1) v += __shfl_xor(v, off, 64);
    return v;
}

// ---------------- dtype detection ----------------
__global__ void k_detect(const void* emb_raw) {
    const bf16* p = (const bf16*)emb_raw;
    int lane = threadIdx.x;
    float v = __bfloat162float(p[lane]);
    bool plaus = (v == v) && (fabsf(v) <= 1e4f) && (v == 0.f || fabsf(v) >= 1e-4f);
    float c = wave_sum(plaus ? 1.f : 0.f);
    if (lane == 0) g_flag = (c >= 52.f) ? 1 : 0;
}

// ---------------- ingest all inputs as fp32 ----------------
struct PtrPack { const void* p[32]; };
__device__ const int D_CNT[32] = {117888,3070,166400,1280,83200,640,327680,1280,163840,640,
                                  64,64,4096,64,4096,64,4096,64,4096,64,
                                  65536,1024,65536,64,64,64,64,64,19648,19648,768,12};
__device__ const int D_OFF[32] = {S_SRC,S_EMB,S_GW0,S_GB0,S_UW0,S_UB0,S_GW1,S_GB1,S_UW1,S_UB1,
                                  S_MLW,S_MLB,S_WQ,S_BQ,S_WK,S_BK,S_WV,S_BV,S_WO,S_BO,
                                  S_FW1,S_FB1,S_FW2,S_FB2,S_L1G,S_L1B,S_L2G,S_L2B,S_WS,S_WT,S_CW,S_CB};
__device__ const int D_CHK[33] = {0,461,473,1123,1128,1453,1456,2736,2741,3381,3384,3385,3386,
                                  3402,3403,3419,3420,3436,3437,3453,3454,3710,3714,3970,3971,
                                  3972,3973,3974,3975,4052,4129,4132,4133};

__global__ void k_ingest(PtrPack pk) {
    int bid = blockIdx.x;
    int s = 0;
    while (s < 31 && bid >= D_CHK[s + 1]) s++;
    int i = (bid - D_CHK[s]) * 256 + threadIdx.x;
    if (i >= D_CNT[s]) return;
    float v;
    if (g_flag) v = __bfloat162float(((const bf16*)pk.p[s])[i]);
    else        v = ((const float*)pk.p[s])[i];
    g_buf[(size_t)D_OFF[s] + i] = v;
}

// ---------------- adjacency ----------------
__global__ void k_adj() {
    int n = blockIdx.x;
    int tid = threadIdx.x;            // 512
    __shared__ float en[EE];
    __shared__ float red[512];
    if (tid < EE) en[tid] = g_buf[S_EMB + n * EE + tid];
    __syncthreads();
    bool act = tid < NN;
    float d = 0.f;
    if (act) {
        #pragma unroll
        for (int e = 0; e < EE; e++) d += en[e] * g_buf[S_EMB + tid * EE + e];
        d = fmaxf(d, 0.f);
    }
    red[tid] = act ? d : -1e30f;
    __syncthreads();
    for (int s = 256; s > 0; s >>= 1) { if (tid < s) red[tid] = fmaxf(red[tid], red[tid + s]); __syncthreads(); }
    float mx = red[0];
    __syncthreads();
    float ex = act ? expf(d - mx) : 0.f;
    red[tid] = ex;
    __syncthreads();
    for (int s = 256; s > 0; s >>= 1) { if (tid < s) red[tid] += red[tid + s]; __syncthreads(); }
    float inv = 1.f / red[0];
    if (act) g_buf[OFF_A + (size_t)n * NN + tid] = ex * inv;
}

// ---------------- per-node GRU weights -> fp32, reordered into Wx/Wh blocks ----------------
__device__ const unsigned SEGC[9] = {0u,5108480u,5147776u,7702016u,7721664u,17781440u,17820736u,22850624u,22870272u};
__device__ const int SEGJ[8]      = {16640,128,8320,64,32768,128,16384,64};
__device__ const int SEGS[8]      = {S_GW0,S_GB0,S_UW0,S_UB0,S_GW1,S_GB1,S_UW1,S_UB1};

__global__ void k_nodew_all() {
    unsigned idx = blockIdx.x * 256u + threadIdx.x;
    if (idx >= 22870272u) return;
    int s = 0;
    while (s < 7 && idx >= SEGC[s + 1]) s++;
    unsigned rem = idx - SEGC[s];
    unsigned J = (unsigned)SEGJ[s];
    unsigned n = rem / J;
    unsigned j = rem - n * J;
    float acc = 0.f;
    const float* eb = g_buf + S_EMB + n * EE;
    const float* w  = g_buf + SEGS[s];
    #pragma unroll
    for (int e = 0; e < EE; e++) acc += eb[e] * w[(size_t)e * J + j];
    size_t dst;
    if (s == 0) {        // gw0: j = (k*65+i)*128+o
        unsigned o = j & 127, kk = j >> 7, k = kk / 65, i = kk % 65;
        dst = (i == 0) ? G0X + ((size_t)n * 2 + k) * 128 + o
                       : G0H + ((size_t)n * 128 + k * 64 + (i - 1)) * 128 + o;
    } else if (s == 1) { dst = BG0 + (size_t)n * 128 + j;
    } else if (s == 2) { // uw0: j = (k*65+i)*64+o
        unsigned o = j & 63, kk = j >> 6, k = kk / 65, i = kk % 65;
        dst = (i == 0) ? U0X + ((size_t)n * 2 + k) * 64 + o
                       : U0H + ((size_t)n * 128 + k * 64 + (i - 1)) * 64 + o;
    } else if (s == 3) { dst = BU0 + (size_t)n * 64 + j;
    } else if (s == 4) { // gw1: j = (k*128+i)*128+o
        unsigned o = j & 127, kk = j >> 7, k = kk >> 7, i = kk & 127;
        dst = (i < 64) ? G1X + ((size_t)n * 128 + k * 64 + i) * 128 + o
                       : G1H + ((size_t)n * 128 + k * 64 + (i - 64)) * 128 + o;
    } else if (s == 5) { dst = BG1 + (size_t)n * 128 + j;
    } else if (s == 6) { // uw1: j = (k*128+i)*64+o
        unsigned o = j & 63, kk = j >> 6, k = kk >> 7, i = kk & 127;
        dst = (i < 64) ? U1X + ((size_t)n * 128 + k * 64 + i) * 64 + o
                       : U1H + ((size_t)n * 128 + k * 64 + (i - 64)) * 64 + o;
    } else {             dst = BU1 + (size_t)n * 64 + j; }
    g_buf[dst] = acc;
}

// ---------------- positional embedding ----------------
__global__ void k_pe() {
    int tid = threadIdx.x;            // 768
    int t = tid >> 6, h = tid & 63;
    float ex = (float)(h & ~1) / 64.f;
    float ang = (float)t * powf(10000.f, -ex);
    g_buf[OFF_PE + tid] = (h & 1) ? cosf(ang) : sinf(ang);
}

__global__ void k_zero(size_t off, int cnt) {
    int i = blockIdx.x * 256 + threadIdx.x;
    if (i < cnt) g_buf[off + i] = 0.f;
}

// ---------------- AX0[t][n][b] = sum_m A[n,m] * src[b,t,m] ----------------
__global__ __launch_bounds__(256) void k_ax0() {
    int t = blockIdx.y;
    int n0 = blockIdx.x * 8;
    int b = threadIdx.x & 31, nl = threadIdx.x >> 5;
    __shared__ float As[8][68];
    __shared__ float xs[32][65];
    float acc = 0.f;
    for (int m0 = 0; m0 < NN; m0 += 64) {
        int jend = min(64, NN - m0);
        for (int idx = threadIdx.x; idx < 8 * 64; idx += 256) {
            int i = idx >> 6, jj = idx & 63;
            int n = n0 + i, m = m0 + jj;
            As[i][jj] = (n < NN && m < NN) ? g_buf[OFF_A + (size_t)n * NN + m] : 0.f;
        }
        for (int idx = threadIdx.x; idx < 32 * 64; idx += 256) {
            int bb = idx >> 6, jj = idx & 63;
            int m = m0 + jj;
            xs[bb][jj] = (m < NN) ? g_buf[S_SRC + ((size_t)bb * TT + t) * NN + m] : 0.f;
        }
        __syncthreads();
        for (int jj = 0; jj < jend; jj++) acc += As[nl][jj] * xs[b][jj];
        __syncthreads();
    }
    int n = n0 + nl;
    if (n < NN) g_buf[OFF_AX0 + ((size_t)t * NN + n) * 32 + b] = acc;
}

// ---------------- standalone agg GEMM (used for AX1, z=12 parallel) ----------------
__global__ __launch_bounds__(256) void k_aggmat(size_t srcOff, size_t dstOff, size_t srcTS, size_t dstTS) {
    int z = blockIdx.z;
    const float* __restrict__ srcp = g_buf + srcOff + (size_t)z * srcTS;
    float* __restrict__ dstp = g_buf + dstOff + (size_t)z * dstTS;
    int n0 = blockIdx.x * 64;
    int col0 = blockIdx.y * 64;
    int tid = threadIdx.x;
    int tn = tid >> 4, tc = tid & 15;
    __shared__ float As[32][68];
    __shared__ float Xs[32][64];
    float acc[4][4];
    #pragma unroll
    for (int i = 0; i < 4; i++)
        #pragma unroll
        for (int j = 0; j < 4; j++) acc[i][j] = 0.f;
    for (int k0 = 0; k0 < NN; k0 += 32) {
        for (int idx = tid; idx < 64 * 32; idx += 256) {
            int k = idx & 31, i = idx >> 5;
            int n = n0 + i, m = k0 + k;
            As[k][i] = (n < NN && m < NN) ? g_buf[OFF_A + (size_t)n * NN + m] : 0.f;
        }
        for (int idx = tid; idx < 32 * 64; idx += 256) {
            int c = idx & 63, k = idx >> 6;
            int m = k0 + k;
            Xs[k][c] = (m < NN) ? srcp[(size_t)m * 2048 + col0 + c] : 0.f;
        }
        __syncthreads();
        #pragma unroll
        for (int k = 0; k < 32; k++) {
            float4 a4 = *(const float4*)&As[k][tn * 4];
            float4 x4 = *(const float4*)&Xs[k][tc * 4];
            const float* aa = (const float*)&a4;
            const float* xx = (const float*)&x4;
            #pragma unroll
            for (int i = 0; i < 4; i++)
                #pragma unroll
                for (int j = 0; j < 4; j++) acc[i][j] += aa[i] * xx[j];
        }
        __syncthreads();
    }
    #pragma unroll
    for (int i = 0; i < 4; i++) {
        int n = n0 + tn * 4 + i;
        if (n < NN) {
            float4 v = make_float4(acc[i][0], acc[i][1], acc[i][2], acc[i][3]);
            *(float4*)&dstp[(size_t)n * 2048 + col0 + tc * 4] = v;
        }
    }
}

// ---------------- x-part preact precompute, layer 0 (K=2); grid (12, NN) t-fastest ----------------
__global__ __launch_bounds__(256) void k_xprep0() {
    int t = blockIdx.x, n = blockIdx.y, tid = threadIdx.x;
    __shared__ float xv[32], ax[32];
    if (tid < 32) {
        xv[tid] = g_buf[S_SRC + ((size_t)tid * TT + t) * NN + n];
        ax[tid] = g_buf[OFF_AX0 + ((size_t)t * NN + n) * 32 + tid];
    }
    __syncthreads();
    size_t pbase = ((size_t)t * NN + n) * 32;
    for (int idx = tid; idx < 4096; idx += 256) {
        int b = idx >> 7, o = idx & 127;
        g_buf[OFF_GXP + (pbase + b) * 128 + o] =
            g_buf[BG0 + (size_t)n * 128 + o]
          + g_buf[G0X + ((size_t)n * 2 + 0) * 128 + o] * xv[b]
          + g_buf[G0X + ((size_t)n * 2 + 1) * 128 + o] * ax[b];
    }
    for (int idx = tid; idx < 2048; idx += 256) {
        int b = idx >> 6, o = idx & 63;
        g_buf[OFF_UXP + (pbase + b) * 64 + o] =
            g_buf[BU0 + (size_t)n * 64 + o]
          + g_buf[U0X + ((size_t)n * 2 + 0) * 64 + o] * xv[b]
          + g_buf[U0X + ((size_t)n * 2 + 1) * 64 + o] * ax[b];
    }
}

// ---------------- x-part preact precompute, layer 1 (K=128); grid (12, NN) t-fastest ----------------
__global__ __launch_bounds__(256, 2) void k_xprep1() {
    __shared__ float smem[12544];
    float* xh = smem;            // [32][136]
    float* Wl = smem + 4352;     // [64][128]
    int t = blockIdx.x, n = blockIdx.y, tid = threadIdx.x;
    size_t pbase = ((size_t)t * NN + n) * 32;
    for (int idx = tid; idx < 4096; idx += 256) {
        int bl = idx >> 7, c = idx & 127;
        float v = (c < 64) ? g_buf[OFF_OUT0 + (pbase + bl) * 64 + c]
                           : g_buf[OFF_AX1 + (pbase + bl) * 64 + (c - 64)];
        xh[bl * 136 + c] = v;
    }
    int o = tid & 63, bl0 = (tid >> 6) * 8;
    float accz[8], accr[8];
    #pragma unroll
    for (int j = 0; j < 8; j++) {
        accz[j] = g_buf[BG1 + (size_t)n * 128 + o];
        accr[j] = g_buf[BG1 + (size_t)n * 128 + o + 64];
    }
    for (int ch = 0; ch < 2; ch++) {
        __syncthreads();
        const float4* wsrc = (const float4*)&g_buf[G1X + (size_t)n * 16384 + ch * 8192];
        float4* wdst = (float4*)Wl;
        for (int idx = tid; idx < 2048; idx += 256) wdst[idx] = wsrc[idx];
        __syncthreads();
        #pragma unroll 4
        for (int kq = 0; kq < 64; kq += 4) {
            float4 xv[8];
            #pragma unroll
            for (int j = 0; j < 8; j++) xv[j] = *(const float4*)&xh[(bl0 + j) * 136 + ch * 64 + kq];
            #pragma unroll
            for (int q = 0; q < 4; q++) {
                float w0 = Wl[(kq + q) * 128 + o];
                float w1 = Wl[(kq + q) * 128 + o + 64];
                #pragma unroll
                for (int j = 0; j < 8; j++) {
                    float xx = ((const float*)&xv[j])[q];
                    accz[j] += xx * w0;
                    accr[j] += xx * w1;
                }
            }
        }
    }
    #pragma unroll
    for (int j = 0; j < 8; j++) {
        g_buf[OFF_GXP + (pbase + bl0 + j) * 128 + o]      = accz[j];
        g_buf[OFF_GXP + (pbase + bl0 + j) * 128 + o + 64] = accr[j];
    }
    float acc[8];
    #pragma unroll
    for (int j = 0; j < 8; j++) acc[j] = g_buf[BU1 + (size_t)n * 64 + o];
    for (int ch = 0; ch < 2; ch++) {
        __syncthreads();
        const float4* wsrc = (const float4*)&g_buf[U1X + (size_t)n * 8192 + ch * 4096];
        float4* wdst = (float4*)Wl;
        for (int idx = tid; idx < 1024; idx += 256) wdst[idx] = wsrc[idx];
        __syncthreads();
        #pragma unroll 4
        for (int kq = 0; kq < 64; kq += 4) {
            float4 xv[8];
            #pragma unroll
            for (int j = 0; j < 8; j++) xv[j] = *(const float4*)&xh[(bl0 + j) * 136 + ch * 64 + kq];
            #pragma unroll
            for (int q = 0; q < 4; q++) {
                float w = Wl[(kq + q) * 64 + o];
                #pragma unroll
                for (int j = 0; j < 8; j++) acc[j] += ((const float*)&xv[j])[q] * w;
            }
        }
    }
    #pragma unroll
    for (int j = 0; j < 8; j++) g_buf[OFF_UXP + (pbase + bl0 + j) * 64 + o] = acc[j];
}

// ---------------- fused gate (r8 form + depth-8 prefetch + t0 skip) ----------------
template<int L>
__global__ __launch_bounds__(256) void k_gateF(int t) {
    constexpr size_t GH = (L == 0) ? G0H : G1H;
    int n = blockIdx.x, tid = threadIdx.x;
    __shared__ float Arow[308];
    __shared__ float xh[32 * 136];   // [b][k]: k<64 = h, k>=64 = A@h
    __shared__ float Wl[64 * 128];
    for (int idx = tid; idx < NN; idx += 256) Arow[idx] = g_buf[OFF_A + (size_t)n * NN + idx];
    for (int idx = tid; idx < 2048; idx += 256) {
        int bl = idx >> 6, c = idx & 63;
        xh[bl * 136 + c] = g_buf[OFF_H + (size_t)n * 2048 + idx];
    }
    __syncthreads();
    // own aggregation: thread owns 8 flat (b,c) cols; depth-8 prefetch for MLP
    float ag[8];
    #pragma unroll
    for (int j = 0; j < 8; j++) ag[j] = 0.f;
    if (t > 0) {
        const float* Hb = g_buf + OFF_H + (size_t)tid * 8;
        int m0 = 0;
        for (; m0 + 8 <= NN; m0 += 8) {
            float4 ha[8], hb[8];
            #pragma unroll
            for (int j = 0; j < 8; j++) {
                const float* p = Hb + (size_t)(m0 + j) * 2048;
                ha[j] = *(const float4*)p;
                hb[j] = *(const float4*)(p + 4);
            }
            #pragma unroll
            for (int j = 0; j < 8; j++) {
                float a = Arow[m0 + j];
                ag[0] += a * ha[j].x; ag[1] += a * ha[j].y;
                ag[2] += a * ha[j].z; ag[3] += a * ha[j].w;
                ag[4] += a * hb[j].x; ag[5] += a * hb[j].y;
                ag[6] += a * hb[j].z; ag[7] += a * hb[j].w;
            }
        }
        for (; m0 < NN; m0++) {
            float a = Arow[m0];
            const float* p = Hb + (size_t)m0 * 2048;
            float4 h0 = *(const float4*)p, h1 = *(const float4*)(p + 4);
            ag[0] += a * h0.x; ag[1] += a * h0.y; ag[2] += a * h0.z; ag[3] += a * h0.w;
            ag[4] += a * h1.x; ag[5] += a * h1.y; ag[6] += a * h1.z; ag[7] += a * h1.w;
        }
    }
    {
        int flat = tid * 8;
        float* dst = &xh[(flat >> 6) * 136 + 64 + (flat & 63)];
        #pragma unroll
        for (int j = 0; j < 8; j++) dst[j] = ag[j];
    }
    __syncthreads();
    int o = tid & 63, bl0 = (tid >> 6) * 8;
    size_t pbase = ((size_t)t * NN + n) * 32;
    float accz[8], accr[8];
    #pragma unroll
    for (int j = 0; j < 8; j++) {
        accz[j] = g_buf[OFF_GXP + (pbase + bl0 + j) * 128 + o];
        accr[j] = g_buf[OFF_GXP + (pbase + bl0 + j) * 128 + o + 64];
    }
    if (t > 0) {
        for (int ch = 0; ch < 2; ch++) {
            __syncthreads();
            const float4* wsrc = (const float4*)&g_buf[GH + (size_t)n * 16384 + ch * 8192];
            float4* wdst = (float4*)Wl;
            for (int idx = tid; idx < 2048; idx += 256) wdst[idx] = wsrc[idx];
            __syncthreads();
            #pragma unroll 4
            for (int kq = 0; kq < 64; kq += 4) {
                float4 xv[8];
                #pragma unroll
                for (int j = 0; j < 8; j++) xv[j] = *(const float4*)&xh[(bl0 + j) * 136 + ch * 64 + kq];
                #pragma unroll
                for (int q = 0; q < 4; q++) {
                    float w0 = Wl[(kq + q) * 128 + o];
                    float w1 = Wl[(kq + q) * 128 + o + 64];
                    #pragma unroll
                    for (int j = 0; j < 8; j++) {
                        float xx = ((const float*)&xv[j])[q];
                        accz[j] += xx * w0;
                        accr[j] += xx * w1;
                    }
                }
            }
        }
    }
    #pragma unroll
    for (int j = 0; j < 8; j++) {
        int b = bl0 + j;
        float z = 1.f / (1.f + expf(-accz[j]));
        float r = 1.f / (1.f + expf(-accr[j]));
        float hv = xh[b * 136 + o];
        g_buf[OFF_ZH + (size_t)n * 2048 + (size_t)b * 64 + o] = z * hv;
        g_buf[OFF_R  + (size_t)n * 2048 + (size_t)b * 64 + o] = r;
    }
}

// ---------------- fused update (r8 form + depth-8 prefetch + t0 skip) ----------------
template<int L, bool WOUT>
__global__ __launch_bounds__(256) void k_updF(int t) {
    constexpr size_t UH = (L == 0) ? U0H : U1H;
    int n = blockIdx.x, tid = threadIdx.x;
    __shared__ float Arow[308];
    __shared__ float xh[32 * 136];   // [b][k]: k<64 = z*h, k>=64 = A@(z*h)
    __shared__ float Wl[64 * 64];
    for (int idx = tid; idx < NN; idx += 256) Arow[idx] = g_buf[OFF_A + (size_t)n * NN + idx];
    for (int idx = tid; idx < 2048; idx += 256) {
        int bl = idx >> 6, c = idx & 63;
        xh[bl * 136 + c] = g_buf[OFF_ZH + (size_t)n * 2048 + idx];
    }
    __syncthreads();
    float ag[8];
    #pragma unroll
    for (int j = 0; j < 8; j++) ag[j] = 0.f;
    if (t > 0) {
        const float* Zb = g_buf + OFF_ZH + (size_t)tid * 8;
        int m0 = 0;
        for (; m0 + 8 <= NN; m0 += 8) {
            float4 ha[8], hb[8];
            #pragma unroll
            for (int j = 0; j < 8; j++) {
                const float* p = Zb + (size_t)(m0 + j) * 2048;
                ha[j] = *(const float4*)p;
                hb[j] = *(const float4*)(p + 4);
            }
            #pragma unroll
            for (int j = 0; j < 8; j++) {
                float a = Arow[m0 + j];
                ag[0] += a * ha[j].x; ag[1] += a * ha[j].y;
                ag[2] += a * ha[j].z; ag[3] += a * ha[j].w;
                ag[4] += a * hb[j].x; ag[5] += a * hb[j].y;
                ag[6] += a * hb[j].z; ag[7] += a * hb[j].w;
            }
        }
        for (; m0 < NN; m0++) {
            float a = Arow[m0];
            const float* p = Zb + (size_t)m0 * 2048;
            float4 h0 = *(const float4*)p, h1 = *(const float4*)(p + 4);
            ag[0] += a * h0.x; ag[1] += a * h0.y; ag[2] += a * h0.z; ag[3] += a * h0.w;
            ag[4] += a * h1.x; ag[5] += a * h1.y; ag[6] += a * h1.z; ag[7] += a * h1.w;
        }
    }
    {
        int flat = tid * 8;
        float* dst = &xh[(flat >> 6) * 136 + 64 + (flat & 63)];
        #pragma unroll
        for (int j = 0; j < 8; j++) dst[j] = ag[j];
    }
    __syncthreads();
    int o = tid & 63, bl0 = (tid >> 6) * 8;
    size_t pbase = ((size_t)t * NN + n) * 32;
    float acc[8];
    #pragma unroll
    for (int j = 0; j < 8; j++) acc[j] = g_buf[OFF_UXP + (pbase + bl0 + j) * 64 + o];
    if (t > 0) {
        for (int ch = 0; ch < 2; ch++) {
            __syncthreads();
            const float4* wsrc = (const float4*)&g_buf[UH + (size_t)n * 8192 + ch * 4096];
            float4* wdst = (float4*)Wl;
            for (int idx = tid; idx < 1024; idx += 256) wdst[idx] = wsrc[idx];
            __syncthreads();
            #pragma unroll 4
            for (int kq = 0; kq < 64; kq += 4) {
                float4 xv[8];
                #pragma unroll
                for (int j = 0; j < 8; j++) xv[j] = *(const float4*)&xh[(bl0 + j) * 136 + ch * 64 + kq];
                #pragma unroll
                for (int q = 0; q < 4; q++) {
                    float w = Wl[(kq + q) * 64 + o];
                    #pragma unroll
                    for (int j = 0; j < 8; j++) acc[j] += ((const float*)&xv[j])[q] * w;
                }
            }
        }
    }
    #pragma unroll
    for (int j = 0; j < 8; j++) {
        int b = bl0 + j;
        size_t base = (size_t)n * 2048 + (size_t)b * 64 + o;
        float hc = tanhf(acc[j]);
        float r = g_buf[OFF_R + base];
        float hold = g_buf[OFF_H + base];
        float hn = r * hold + (1.f - r) * hc;
        g_buf[OFF_H + base] = hn;
        if constexpr (WOUT) g_buf[OFF_OUT0 + (pbase + b) * 64 + o] = hn;
    }
}

// ---------------- fused attention (t=T-1 only) + LN1; 4 (b,n) per block ----------------
__global__ __launch_bounds__(256) void k_attn() {
    int wid = threadIdx.x >> 6;
    int lane = threadIdx.x & 63;
    int g = blockIdx.x * 4 + wid;
    int b = g / NN, n = g - b * NN;
    __shared__ float x[4][TT][HH], kk[4][TT][HH], vv[4][TT][HH];
    __shared__ float q[4][HH], o1[4][HH], sc[4][HEADS][TT], aw[4][HEADS][TT];
    float mw = g_buf[S_MLW + lane];
    float mb = g_buf[S_MLB + lane];
    #pragma unroll
    for (int tt = 0; tt < TT; tt++) {
        float s = g_buf[S_SRC + ((size_t)b * TT + tt) * NN + n];
        x[wid][tt][lane] = s * mw + mb + g_buf[OFF_PE + tt * HH + lane];
    }
    __syncthreads();
    float ka[TT], va[TT];
    #pragma unroll
    for (int tt = 0; tt < TT; tt++) { ka[tt] = g_buf[S_BK + lane]; va[tt] = g_buf[S_BV + lane]; }
    float qa = g_buf[S_BQ + lane];
    for (int i = 0; i < HH; i++) {
        float wkv = g_buf[S_WK + i * HH + lane];
        float wvv = g_buf[S_WV + i * HH + lane];
        qa += x[wid][TT - 1][i] * g_buf[S_WQ + i * HH + lane];
        #pragma unroll
        for (int tt = 0; tt < TT; tt++) {
            float xv = x[wid][tt][i];
            ka[tt] += xv * wkv;
            va[tt] += xv * wvv;
        }
    }
    #pragma unroll
    for (int tt = 0; tt < TT; tt++) { kk[wid][tt][lane] = ka[tt]; vv[wid][tt][lane] = va[tt]; }
    q[wid][lane] = qa;
    __syncthreads();
    if (lane < HEADS * TT) {
        int head = lane / TT, ts = lane - head * TT;
        float s = 0.f;
        #pragma unroll
        for (int d = 0; d < HD; d++) s += q[wid][head * HD + d] * kk[wid][ts][head * HD + d];
        sc[wid][head][ts] = s * 0.25f;
    }
    __syncthreads();
    if (lane < HEADS * TT) {
        int head = lane / TT, ts = lane - head * TT;
        float mx = -1e30f;
        #pragma unroll
        for (int j = 0; j < TT; j++) mx = fmaxf(mx, sc[wid][head][j]);
        float sm = 0.f;
        #pragma unroll
        for (int j = 0; j < TT; j++) sm += expf(sc[wid][head][j] - mx);
        aw[wid][head][ts] = expf(sc[wid][head][ts] - mx) / sm;
    }
    __syncthreads();
    int head = lane >> 4;
    float oa = 0.f;
    #pragma unroll
    for (int tt = 0; tt < TT; tt++) oa += aw[wid][head][tt] * vv[wid][tt][lane];
    o1[wid][lane] = oa;
    __syncthreads();
    float acc = g_buf[S_BO + lane];
    for (int i = 0; i < HH; i++) acc += o1[wid][i] * g_buf[S_WO + i * HH + lane];
    float res = x[wid][TT - 1][lane] + acc;
    float mean = wave_sum(res) * (1.f / 64.f);
    float dv = res - mean;
    float var = wave_sum(dv * dv) * (1.f / 64.f);
    float ln = dv * rsqrtf(var + 1e-5f) * g_buf[S_L1G + lane] + g_buf[S_L1B + lane];
    g_buf[OFF_OLN + ((size_t)b * NN + n) * HH + lane] = ln;
}

// ---------------- FFN + LN2; 8 tokens per block ----------------
__global__ __launch_bounds__(256) void k_ffn() {
    int tok0 = blockIdx.x * 8;
    int tid = threadIdx.x;
    __shared__ float ox[8][HH];
    __shared__ float hid[8][1024];
    for (int idx = tid; idx < 8 * HH; idx += 256) {
        int tk = idx >> 6, hh = idx & 63;
        ox[tk][hh] = g_buf[OFF_OLN + (size_t)(tok0 + tk) * HH + hh];
    }
    __syncthreads();
    #pragma unroll
    for (int p = 0; p < 4; p++) {
        int j = tid + 256 * p;
        float bj = g_buf[S_FB1 + j];
        float a[8];
        #pragma unroll
        for (int tk = 0; tk < 8; tk++) a[tk] = bj;
        for (int i = 0; i < HH; i++) {
            float w = g_buf[S_FW1 + (size_t)i * 1024 + j];
            #pragma unroll
            for (int tk = 0; tk < 8; tk++) a[tk] += ox[tk][i] * w;
        }
        #pragma unroll
        for (int tk = 0; tk < 8; tk++) hid[tk][j] = fmaxf(a[tk], 0.f);
    }
    __syncthreads();
    int tk = tid >> 6, hh = tid & 63;
    float acc0 = g_buf[S_FB2 + hh], acc1 = acc0;
    for (int j = 0; j < 1024; j++) {
        float w = g_buf[S_FW2 + (size_t)j * HH + hh];
        acc0 += hid[tk][j] * w;
        acc1 += hid[tk + 4][j] * w;
    }
    #pragma unroll
    for (int ph = 0; ph < 2; ph++) {
        int tkk = tk + 4 * ph;
        float res = ox[tkk][hh] + (ph ? acc1 : acc0);
        float mean = wave_sum(res) * (1.f / 64.f);
        float dv = res - mean;
        float var = wave_sum(dv * dv) * (1.f / 64.f);
        float ln = dv * rsqrtf(var + 1e-5f) * g_buf[S_L2G + hh] + g_buf[S_L2B + hh];
        g_buf[OFF_O2 + (size_t)(tok0 + tkk) * HH + hh] = ln;
    }
}

// ---------------- final combine + horizon conv ----------------
__global__ void k_final(void* out) {
    int n = blockIdx.x, b = blockIdx.y;
    int h = threadIdx.x;
    __shared__ float comb[HH];
    comb[h] = g_buf[OFF_H + ((size_t)n * 32 + b) * 64 + h] * g_buf[S_WS + n * HH + h]
            + g_buf[OFF_O2 + ((size_t)b * NN + n) * 64 + h] * g_buf[S_WT + n * HH + h];
    __syncthreads();
    if (h < HORIZON) {
        float acc = g_buf[S_CB + h];
        #pragma unroll
        for (int i = 0; i < HH; i++) acc += comb[i] * g_buf[S_CW + h * HH + i];
        size_t oi = ((size_t)b * HORIZON + h) * NN + n;
        if (g_flag) ((bf16*)out)[oi] = __float2bfloat16(acc);
        else        ((float*)out)[oi] = acc;
    }
}

extern "C" void kernel_launch(void* const* d_in, const int* in_sizes, int n_in,
                              void* d_out, int out_size, void* d_ws, size_t ws_size,
                              hipStream_t stream) {
    PtrPack pk;
    for (int i = 0; i < 32; i++) pk.p[i] = d_in[i];

    k_detect<<<1, 64, 0, stream>>>(d_in[1]);
    k_ingest<<<4133, 256, 0, stream>>>(pk);
    k_adj<<<NN, 512, 0, stream>>>();
    k_nodew_all<<<89337, 256, 0, stream>>>();
    k_pe<<<1, 768, 0, stream>>>();
    k_ax0<<<dim3(39, 12), 256, 0, stream>>>();
    k_xprep0<<<dim3(12, NN), 256, 0, stream>>>();

    // ---- GRU layer 0: 2 fused dispatches per step (grid NN, r8 form) ----
    k_zero<<<2456, 256, 0, stream>>>(OFF_H, 628736);
    for (int t = 0; t < TT; t++) {
        k_gateF<0><<<NN, 256, 0, stream>>>(t);
        k_updF<0, true><<<NN, 256, 0, stream>>>(t);
    }
    // ---- layer-1 x-part precompute (t-parallel) ----
    k_aggmat<<<dim3(5, 32, 12), 256, 0, stream>>>(OFF_OUT0, OFF_AX1, 628736, 628736);
    k_xprep1<<<dim3(12, NN), 256, 0, stream>>>();
    // ---- GRU layer 1 ----
    k_zero<<<2456, 256, 0, stream>>>(OFF_H, 628736);
    for (int t = 0; t < TT; t++) {
        k_gateF<1><<<NN, 256, 0, stream>>>(t);
        k_updF<1, false><<<NN, 256, 0, stream>>>(t);
    }
    // ---- transformer branch ----
    k_attn<<<2456, 256, 0, stream>>>();
    k_ffn<<<1228, 256, 0, stream>>>();
    // ---- combine + conv ----
    k_final<<<dim3(NN, BB), 64, 0, stream>>>(d_out);
}

// Round 11
// 3288.094 us; speedup vs baseline: 1.5710x; 1.0174x over previous
//
#include <hip/hip_runtime.h>
#include <hip/hip_bf16.h>

typedef __hip_bfloat16 bf16;

constexpr int NN = 307, TT = 12, BB = 32, HH = 64, EE = 10, HEADS = 4, HD = 16, HORIZON = 12;

// ---------------- staged fp32 input offsets ----------------
constexpr int S_SRC = 0,       S_EMB = 117888,  S_GW0 = 120958,  S_GB0 = 287358,
              S_UW0 = 288638,  S_UB0 = 371838,  S_GW1 = 372478,  S_GB1 = 700158,
              S_UW1 = 701438,  S_UB1 = 865278,  S_MLW = 865918,  S_MLB = 865982,
              S_WQ  = 866046,  S_BQ  = 870142,  S_WK  = 870206,  S_BK  = 874302,
              S_WV  = 874366,  S_BV  = 878462,  S_WO  = 878526,  S_BO  = 882622,
              S_FW1 = 882686,  S_FB1 = 948222,  S_FW2 = 949246,  S_FB2 = 1014782,
              S_L1G = 1014846, S_L1B = 1014910, S_L2G = 1014974, S_L2B = 1015038,
              S_WS  = 1015102, S_WT  = 1034750, S_CW  = 1054398, S_CB  = 1055166;

// ---------------- fp32 work regions ----------------
constexpr size_t OFF_A    = 1055178;   // 307*307
constexpr size_t OFF_OUT0 = 1149427;   // [t][n][b][c] 12*307*2048
constexpr size_t OFF_H0   = 8694259;   // [n][b][c] 307*2048 (layer 0)
constexpr size_t OFF_ZH0  = 9322995;
constexpr size_t OFF_R0   = 9951731;
constexpr size_t OFF_AX0  = 11209203;  // [t][n][b] 12*307*32
constexpr size_t OFF_AX1  = 11327091;  // [t][n][b][c] 12*307*2048
constexpr size_t OFF_PE   = 18871923;  // 12*64
constexpr size_t OFF_OLN  = 18872691;
constexpr size_t OFF_O2   = 19501427;
constexpr size_t OFF_WB   = 20130164;  // fp32 reordered per-node GRU weights

// Reordered weight blocks (fp32; bf16 storage fails: scan amplifies to 0.19 absmax — r3)
constexpr size_t G0X = OFF_WB +        0;  // 307*2*128
constexpr size_t G0H = OFF_WB +    78592;  // 307*128*128
constexpr size_t BG0 = OFF_WB +  5108480;  // 307*128
constexpr size_t U0X = OFF_WB +  5147776;  // 307*2*64
constexpr size_t U0H = OFF_WB +  5187072;  // 307*128*64
constexpr size_t BU0 = OFF_WB +  7702016;  // 307*64
constexpr size_t G1X = OFF_WB +  7721664;  // 307*128*128
constexpr size_t G1H = OFF_WB + 12751552;  // 307*128*128
constexpr size_t BG1 = OFF_WB + 17781440;  // 307*128
constexpr size_t U1X = OFF_WB + 17820736;  // 307*128*64
constexpr size_t U1H = OFF_WB + 20335680;  // 307*128*64
constexpr size_t BU1 = OFF_WB + 22850624;  // 307*64
constexpr size_t OFF_GXP = OFF_WB + 22870272;       // [t][n][b][128] L0 preact x-part (bias folded)
constexpr size_t OFF_UXP = OFF_GXP + 15089664;      // [t][n][b][64]
constexpr size_t OFF_H1  = OFF_UXP + 7544832;       // layer-1 state buffers
constexpr size_t OFF_ZH1 = OFF_H1  + 628736;
constexpr size_t OFF_R1  = OFF_ZH1 + 628736;
constexpr size_t G_TOTAL = OFF_R1  + 628736 + 4096;

// r10->r11: L0/L1 PIPELINED lag-1. Superstep s runs L0(t=s) and L1(t=s-1) merged
// in one 614-block dispatch (2.4 blocks/CU, imbalance 1.67->1.25; launch overhead
// halves). k_xprep1 deleted: its K=128 x-part GEMM is folded into the L1 blocks
// (acc=BG1/BU1 + G1X/U1X @ [out0;AX1] + G1H/U1H @ [h;A@h] — bit-identical order).
// AX1[t] computed by a small per-t aggmat at superstep start. 38 serial dispatches.

__device__ float g_buf[G_TOTAL];
__device__ int g_flag;   // 1 = inputs are bf16, 0 = fp32

__device__ __forceinline__ float wave_sum(float v) {
    #pragma unroll
    for (int off = 32; off > 0; off >>= 1) v += __shfl_xor(v, off, 64);
    return v;
}

// ---------------- dtype detection ----------------
__global__ void k_detect(const void* emb_raw) {
    const bf16* p = (const bf16*)emb_raw;
    int lane = threadIdx.x;
    float v = __bfloat162float(p[lane]);
    bool plaus = (v == v) && (fabsf(v) <= 1e4f) && (v == 0.f || fabsf(v) >= 1e-4f);
    float c = wave_sum(plaus ? 1.f : 0.f);
    if (lane == 0) g_flag = (c >= 52.f) ? 1 : 0;
}

// ---------------- ingest all inputs as fp32 ----------------
struct PtrPack { const void* p[32]; };
__device__ const int D_CNT[32] = {117888,3070,166400,1280,83200,640,327680,1280,163840,640,
                                  64,64,4096,64,4096,64,4096,64,4096,64,
                                  65536,1024,65536,64,64,64,64,64,19648,19648,768,12};
__device__ const int D_OFF[32] = {S_SRC,S_EMB,S_GW0,S_GB0,S_UW0,S_UB0,S_GW1,S_GB1,S_UW1,S_UB1,
                                  S_MLW,S_MLB,S_WQ,S_BQ,S_WK,S_BK,S_WV,S_BV,S_WO,S_BO,
                                  S_FW1,S_FB1,S_FW2,S_FB2,S_L1G,S_L1B,S_L2G,S_L2B,S_WS,S_WT,S_CW,S_CB};
__device__ const int D_CHK[33] = {0,461,473,1123,1128,1453,1456,2736,2741,3381,3384,3385,3386,
                                  3402,3403,3419,3420,3436,3437,3453,3454,3710,3714,3970,3971,
                                  3972,3973,3974,3975,4052,4129,4132,4133};

__global__ void k_ingest(PtrPack pk) {
    int bid = blockIdx.x;
    int s = 0;
    while (s < 31 && bid >= D_CHK[s + 1]) s++;
    int i = (bid - D_CHK[s]) * 256 + threadIdx.x;
    if (i >= D_CNT[s]) return;
    float v;
    if (g_flag) v = __bfloat162float(((const bf16*)pk.p[s])[i]);
    else        v = ((const float*)pk.p[s])[i];
    g_buf[(size_t)D_OFF[s] + i] = v;
}

// ---------------- adjacency ----------------
__global__ void k_adj() {
    int n = blockIdx.x;
    int tid = threadIdx.x;            // 512
    __shared__ float en[EE];
    __shared__ float red[512];
    if (tid < EE) en[tid] = g_buf[S_EMB + n * EE + tid];
    __syncthreads();
    bool act = tid < NN;
    float d = 0.f;
    if (act) {
        #pragma unroll
        for (int e = 0; e < EE; e++) d += en[e] * g_buf[S_EMB + tid * EE + e];
        d = fmaxf(d, 0.f);
    }
    red[tid] = act ? d : -1e30f;
    __syncthreads();
    for (int s = 256; s > 0; s >>= 1) { if (tid < s) red[tid] = fmaxf(red[tid], red[tid + s]); __syncthreads(); }
    float mx = red[0];
    __syncthreads();
    float ex = act ? expf(d - mx) : 0.f;
    red[tid] = ex;
    __syncthreads();
    for (int s = 256; s > 0; s >>= 1) { if (tid < s) red[tid] += red[tid + s]; __syncthreads(); }
    float inv = 1.f / red[0];
    if (act) g_buf[OFF_A + (size_t)n * NN + tid] = ex * inv;
}

// ---------------- per-node GRU weights -> fp32, reordered into Wx/Wh blocks ----------------
__device__ const unsigned SEGC[9] = {0u,5108480u,5147776u,7702016u,7721664u,17781440u,17820736u,22850624u,22870272u};
__device__ const int SEGJ[8]      = {16640,128,8320,64,32768,128,16384,64};
__device__ const int SEGS[8]      = {S_GW0,S_GB0,S_UW0,S_UB0,S_GW1,S_GB1,S_UW1,S_UB1};

__global__ void k_nodew_all() {
    unsigned idx = blockIdx.x * 256u + threadIdx.x;
    if (idx >= 22870272u) return;
    int s = 0;
    while (s < 7 && idx >= SEGC[s + 1]) s++;
    unsigned rem = idx - SEGC[s];
    unsigned J = (unsigned)SEGJ[s];
    unsigned n = rem / J;
    unsigned j = rem - n * J;
    float acc = 0.f;
    const float* eb = g_buf + S_EMB + n * EE;
    const float* w  = g_buf + SEGS[s];
    #pragma unroll
    for (int e = 0; e < EE; e++) acc += eb[e] * w[(size_t)e * J + j];
    size_t dst;
    if (s == 0) {        // gw0: j = (k*65+i)*128+o
        unsigned o = j & 127, kk = j >> 7, k = kk / 65, i = kk % 65;
        dst = (i == 0) ? G0X + ((size_t)n * 2 + k) * 128 + o
                       : G0H + ((size_t)n * 128 + k * 64 + (i - 1)) * 128 + o;
    } else if (s == 1) { dst = BG0 + (size_t)n * 128 + j;
    } else if (s == 2) { // uw0: j = (k*65+i)*64+o
        unsigned o = j & 63, kk = j >> 6, k = kk / 65, i = kk % 65;
        dst = (i == 0) ? U0X + ((size_t)n * 2 + k) * 64 + o
                       : U0H + ((size_t)n * 128 + k * 64 + (i - 1)) * 64 + o;
    } else if (s == 3) { dst = BU0 + (size_t)n * 64 + j;
    } else if (s == 4) { // gw1: j = (k*128+i)*128+o
        unsigned o = j & 127, kk = j >> 7, k = kk >> 7, i = kk & 127;
        dst = (i < 64) ? G1X + ((size_t)n * 128 + k * 64 + i) * 128 + o
                       : G1H + ((size_t)n * 128 + k * 64 + (i - 64)) * 128 + o;
    } else if (s == 5) { dst = BG1 + (size_t)n * 128 + j;
    } else if (s == 6) { // uw1: j = (k*128+i)*64+o
        unsigned o = j & 63, kk = j >> 6, k = kk >> 7, i = kk & 127;
        dst = (i < 64) ? U1X + ((size_t)n * 128 + k * 64 + i) * 64 + o
                       : U1H + ((size_t)n * 128 + k * 64 + (i - 64)) * 64 + o;
    } else {             dst = BU1 + (size_t)n * 64 + j; }
    g_buf[dst] = acc;
}

// ---------------- positional embedding ----------------
__global__ void k_pe() {
    int tid = threadIdx.x;            // 768
    int t = tid >> 6, h = tid & 63;
    float ex = (float)(h & ~1) / 64.f;
    float ang = (float)t * powf(10000.f, -ex);
    g_buf[OFF_PE + tid] = (h & 1) ? cosf(ang) : sinf(ang);
}

__global__ void k_zero(size_t off, int cnt) {
    int i = blockIdx.x * 256 + threadIdx.x;
    if (i < cnt) g_buf[off + i] = 0.f;
}

// ---------------- AX0[t][n][b] = sum_m A[n,m] * src[b,t,m] ----------------
__global__ __launch_bounds__(256) void k_ax0() {
    int t = blockIdx.y;
    int n0 = blockIdx.x * 8;
    int b = threadIdx.x & 31, nl = threadIdx.x >> 5;
    __shared__ float As[8][68];
    __shared__ float xs[32][65];
    float acc = 0.f;
    for (int m0 = 0; m0 < NN; m0 += 64) {
        int jend = min(64, NN - m0);
        for (int idx = threadIdx.x; idx < 8 * 64; idx += 256) {
            int i = idx >> 6, jj = idx & 63;
            int n = n0 + i, m = m0 + jj;
            As[i][jj] = (n < NN && m < NN) ? g_buf[OFF_A + (size_t)n * NN + m] : 0.f;
        }
        for (int idx = threadIdx.x; idx < 32 * 64; idx += 256) {
            int bb = idx >> 6, jj = idx & 63;
            int m = m0 + jj;
            xs[bb][jj] = (m < NN) ? g_buf[S_SRC + ((size_t)bb * TT + t) * NN + m] : 0.f;
        }
        __syncthreads();
        for (int jj = 0; jj < jend; jj++) acc += As[nl][jj] * xs[b][jj];
        __syncthreads();
    }
    int n = n0 + nl;
    if (n < NN) g_buf[OFF_AX0 + ((size_t)t * NN + n) * 32 + b] = acc;
}

// ---------------- agg GEMM (per-t AX1) ----------------
__global__ __launch_bounds__(256) void k_aggmat(size_t srcOff, size_t dstOff) {
    const float* __restrict__ srcp = g_buf + srcOff;
    float* __restrict__ dstp = g_buf + dstOff;
    int n0 = blockIdx.x * 64;
    int col0 = blockIdx.y * 64;
    int tid = threadIdx.x;
    int tn = tid >> 4, tc = tid & 15;
    __shared__ float As[32][68];
    __shared__ float Xs[32][64];
    float acc[4][4];
    #pragma unroll
    for (int i = 0; i < 4; i++)
        #pragma unroll
        for (int j = 0; j < 4; j++) acc[i][j] = 0.f;
    for (int k0 = 0; k0 < NN; k0 += 32) {
        for (int idx = tid; idx < 64 * 32; idx += 256) {
            int k = idx & 31, i = idx >> 5;
            int n = n0 + i, m = k0 + k;
            As[k][i] = (n < NN && m < NN) ? g_buf[OFF_A + (size_t)n * NN + m] : 0.f;
        }
        for (int idx = tid; idx < 32 * 64; idx += 256) {
            int c = idx & 63, k = idx >> 6;
            int m = k0 + k;
            Xs[k][c] = (m < NN) ? srcp[(size_t)m * 2048 + col0 + c] : 0.f;
        }
        __syncthreads();
        #pragma unroll
        for (int k = 0; k < 32; k++) {
            float4 a4 = *(const float4*)&As[k][tn * 4];
            float4 x4 = *(const float4*)&Xs[k][tc * 4];
            const float* aa = (const float*)&a4;
            const float* xx = (const float*)&x4;
            #pragma unroll
            for (int i = 0; i < 4; i++)
                #pragma unroll
                for (int j = 0; j < 4; j++) acc[i][j] += aa[i] * xx[j];
        }
        __syncthreads();
    }
    #pragma unroll
    for (int i = 0; i < 4; i++) {
        int n = n0 + tn * 4 + i;
        if (n < NN) {
            float4 v = make_float4(acc[i][0], acc[i][1], acc[i][2], acc[i][3]);
            *(float4*)&dstp[(size_t)n * 2048 + col0 + tc * 4] = v;
        }
    }
}

// ---------------- x-part preact precompute, layer 0 (K=2); grid (12, NN) ----------------
__global__ __launch_bounds__(256) void k_xprep0() {
    int t = blockIdx.x, n = blockIdx.y, tid = threadIdx.x;
    __shared__ float xv[32], ax[32];
    if (tid < 32) {
        xv[tid] = g_buf[S_SRC + ((size_t)tid * TT + t) * NN + n];
        ax[tid] = g_buf[OFF_AX0 + ((size_t)t * NN + n) * 32 + tid];
    }
    __syncthreads();
    size_t pbase = ((size_t)t * NN + n) * 32;
    for (int idx = tid; idx < 4096; idx += 256) {
        int b = idx >> 7, o = idx & 127;
        g_buf[OFF_GXP + (pbase + b) * 128 + o] =
            g_buf[BG0 + (size_t)n * 128 + o]
          + g_buf[G0X + ((size_t)n * 2 + 0) * 128 + o] * xv[b]
          + g_buf[G0X + ((size_t)n * 2 + 1) * 128 + o] * ax[b];
    }
    for (int idx = tid; idx < 2048; idx += 256) {
        int b = idx >> 6, o = idx & 63;
        g_buf[OFF_UXP + (pbase + b) * 64 + o] =
            g_buf[BU0 + (size_t)n * 64 + o]
          + g_buf[U0X + ((size_t)n * 2 + 0) * 64 + o] * xv[b]
          + g_buf[U0X + ((size_t)n * 2 + 1) * 64 + o] * ax[b];
    }
}

// ======== merged pipelined gate: blocks [0,NN) = L0 t=s, [NN,2NN) = L1 t=s-1 ========
// smem layout (floats): Arow 308 | xh 32*136 | xx 32*136 | Wl 32*128
__global__ __launch_bounds__(256) void k_gateM(int s) {
    __shared__ float smem[13108];
    float* Arow = smem;
    float* xh   = smem + 308;
    float* xx   = smem + 4660;
    float* Wl   = smem + 9012;
    int lay = (blockIdx.x >= NN) ? 1 : 0;
    int n = blockIdx.x - lay * NN;
    int t = lay ? (s - 1) : s;
    if (t < 0 || t >= TT) return;
    int tid = threadIdx.x;
    size_t Hoff  = lay ? OFF_H1 : OFF_H0;
    for (int idx = tid; idx < NN; idx += 256) Arow[idx] = g_buf[OFF_A + (size_t)n * NN + idx];
    for (int idx = tid; idx < 2048; idx += 256) {
        int bl = idx >> 6, c = idx & 63;
        xh[bl * 136 + c] = g_buf[Hoff + (size_t)n * 2048 + idx];
    }
    if (lay) {
        size_t pb = ((size_t)t * NN + n) * 2048;
        for (int idx = tid; idx < 4096; idx += 256) {
            int bl = idx >> 7, c = idx & 127;
            float v = (c < 64) ? g_buf[OFF_OUT0 + pb + bl * 64 + c]
                               : g_buf[OFF_AX1 + pb + bl * 64 + (c - 64)];
            xx[bl * 136 + c] = v;
        }
    }
    __syncthreads();
    // own-agg A[n,:] @ H -> xh cols 64..127 (depth-8 prefetch; skip if t==0, H=0)
    float ag[8];
    #pragma unroll
    for (int j = 0; j < 8; j++) ag[j] = 0.f;
    if (t > 0) {
        const float* Hb = g_buf + Hoff + (size_t)tid * 8;
        int m0 = 0;
        for (; m0 + 8 <= NN; m0 += 8) {
            float4 ha[8], hb[8];
            #pragma unroll
            for (int j = 0; j < 8; j++) {
                const float* p = Hb + (size_t)(m0 + j) * 2048;
                ha[j] = *(const float4*)p;
                hb[j] = *(const float4*)(p + 4);
            }
            #pragma unroll
            for (int j = 0; j < 8; j++) {
                float a = Arow[m0 + j];
                ag[0] += a * ha[j].x; ag[1] += a * ha[j].y;
                ag[2] += a * ha[j].z; ag[3] += a * ha[j].w;
                ag[4] += a * hb[j].x; ag[5] += a * hb[j].y;
                ag[6] += a * hb[j].z; ag[7] += a * hb[j].w;
            }
        }
        for (; m0 < NN; m0++) {
            float a = Arow[m0];
            const float* p = Hb + (size_t)m0 * 2048;
            float4 h0 = *(const float4*)p, h1 = *(const float4*)(p + 4);
            ag[0] += a * h0.x; ag[1] += a * h0.y; ag[2] += a * h0.z; ag[3] += a * h0.w;
            ag[4] += a * h1.x; ag[5] += a * h1.y; ag[6] += a * h1.z; ag[7] += a * h1.w;
        }
    }
    {
        int flat = tid * 8;
        float* dst = &xh[(flat >> 6) * 136 + 64 + (flat & 63)];
        #pragma unroll
        for (int j = 0; j < 8; j++) dst[j] = ag[j];
    }
    __syncthreads();
    int o = tid & 63, bl0 = (tid >> 6) * 8;
    size_t pbase = ((size_t)t * NN + n) * 32;
    float accz[8], accr[8];
    if (lay) {
        #pragma unroll
        for (int j = 0; j < 8; j++) {
            accz[j] = g_buf[BG1 + (size_t)n * 128 + o];
            accr[j] = g_buf[BG1 + (size_t)n * 128 + o + 64];
        }
    } else {
        #pragma unroll
        for (int j = 0; j < 8; j++) {
            accz[j] = g_buf[OFF_GXP + (pbase + bl0 + j) * 128 + o];
            accr[j] = g_buf[OFF_GXP + (pbase + bl0 + j) * 128 + o + 64];
        }
    }
    // chunked K=32 GEMM passes: L1 does G1X@xx then (t>0) G1H@xh; L0 does (t>0) G0H@xh
    for (int pass = 0; pass < 2; pass++) {
        const float* Wbase;
        const float* X;
        if (lay) {
            if (pass == 0) { Wbase = g_buf + G1X + (size_t)n * 16384; X = xx; }
            else           { if (t == 0) break; Wbase = g_buf + G1H + (size_t)n * 16384; X = xh; }
        } else {
            if (pass == 0) { if (t == 0) break; Wbase = g_buf + G0H + (size_t)n * 16384; X = xh; }
            else break;
        }
        for (int ch = 0; ch < 4; ch++) {
            __syncthreads();
            const float4* wsrc = (const float4*)(Wbase + ch * 4096);
            float4* wdst = (float4*)Wl;
            for (int idx = tid; idx < 1024; idx += 256) wdst[idx] = wsrc[idx];
            __syncthreads();
            #pragma unroll 4
            for (int kq = 0; kq < 32; kq += 4) {
                float4 xv[8];
                #pragma unroll
                for (int j = 0; j < 8; j++) xv[j] = *(const float4*)&X[(bl0 + j) * 136 + ch * 32 + kq];
                #pragma unroll
                for (int q = 0; q < 4; q++) {
                    float w0 = Wl[(kq + q) * 128 + o];
                    float w1 = Wl[(kq + q) * 128 + o + 64];
                    #pragma unroll
                    for (int j = 0; j < 8; j++) {
                        float xxv = ((const float*)&xv[j])[q];
                        accz[j] += xxv * w0;
                        accr[j] += xxv * w1;
                    }
                }
            }
        }
    }
    size_t ZHoff = lay ? OFF_ZH1 : OFF_ZH0;
    size_t Roff  = lay ? OFF_R1 : OFF_R0;
    #pragma unroll
    for (int j = 0; j < 8; j++) {
        int b = bl0 + j;
        float z = 1.f / (1.f + expf(-accz[j]));
        float r = 1.f / (1.f + expf(-accr[j]));
        float hv = xh[b * 136 + o];
        g_buf[ZHoff + (size_t)n * 2048 + (size_t)b * 64 + o] = z * hv;
        g_buf[Roff  + (size_t)n * 2048 + (size_t)b * 64 + o] = r;
    }
}

// ======== merged pipelined update ========
__global__ __launch_bounds__(256) void k_updM(int s) {
    __shared__ float smem[13108];
    float* Arow = smem;
    float* xh   = smem + 308;
    float* xx   = smem + 4660;
    float* Wl   = smem + 9012;
    int lay = (blockIdx.x >= NN) ? 1 : 0;
    int n = blockIdx.x - lay * NN;
    int t = lay ? (s - 1) : s;
    if (t < 0 || t >= TT) return;
    int tid = threadIdx.x;
    size_t ZHoff = lay ? OFF_ZH1 : OFF_ZH0;
    for (int idx = tid; idx < NN; idx += 256) Arow[idx] = g_buf[OFF_A + (size_t)n * NN + idx];
    for (int idx = tid; idx < 2048; idx += 256) {
        int bl = idx >> 6, c = idx & 63;
        xh[bl * 136 + c] = g_buf[ZHoff + (size_t)n * 2048 + idx];
    }
    if (lay) {
        size_t pb = ((size_t)t * NN + n) * 2048;
        for (int idx = tid; idx < 4096; idx += 256) {
            int bl = idx >> 7, c = idx & 127;
            float v = (c < 64) ? g_buf[OFF_OUT0 + pb + bl * 64 + c]
                               : g_buf[OFF_AX1 + pb + bl * 64 + (c - 64)];
            xx[bl * 136 + c] = v;
        }
    }
    __syncthreads();
    float ag[8];
    #pragma unroll
    for (int j = 0; j < 8; j++) ag[j] = 0.f;
    if (t > 0) {
        const float* Zb = g_buf + ZHoff + (size_t)tid * 8;
        int m0 = 0;
        for (; m0 + 8 <= NN; m0 += 8) {
            float4 ha[8], hb[8];
            #pragma unroll
            for (int j = 0; j < 8; j++) {
                const float* p = Zb + (size_t)(m0 + j) * 2048;
                ha[j] = *(const float4*)p;
                hb[j] = *(const float4*)(p + 4);
            }
            #pragma unroll
            for (int j = 0; j < 8; j++) {
                float a = Arow[m0 + j];
                ag[0] += a * ha[j].x; ag[1] += a * ha[j].y;
                ag[2] += a * ha[j].z; ag[3] += a * ha[j].w;
                ag[4] += a * hb[j].x; ag[5] += a * hb[j].y;
                ag[6] += a * hb[j].z; ag[7] += a * hb[j].w;
            }
        }
        for (; m0 < NN; m0++) {
            float a = Arow[m0];
            const float* p = Zb + (size_t)m0 * 2048;
            float4 h0 = *(const float4*)p, h1 = *(const float4*)(p + 4);
            ag[0] += a * h0.x; ag[1] += a * h0.y; ag[2] += a * h0.z; ag[3] += a * h0.w;
            ag[4] += a * h1.x; ag[5] += a * h1.y; ag[6] += a * h1.z; ag[7] += a * h1.w;
        }
    }
    {
        int flat = tid * 8;
        float* dst = &xh[(flat >> 6) * 136 + 64 + (flat & 63)];
        #pragma unroll
        for (int j = 0; j < 8; j++) dst[j] = ag[j];
    }
    __syncthreads();
    int o = tid & 63, bl0 = (tid >> 6) * 8;
    size_t pbase = ((size_t)t * NN + n) * 32;
    float acc[8];
    if (lay) {
        #pragma unroll
        for (int j = 0; j < 8; j++) acc[j] = g_buf[BU1 + (size_t)n * 64 + o];
    } else {
        #pragma unroll
        for (int j = 0; j < 8; j++) acc[j] = g_buf[OFF_UXP + (pbase + bl0 + j) * 64 + o];
    }
    for (int pass = 0; pass < 2; pass++) {
        const float* Wbase;
        const float* X;
        if (lay) {
            if (pass == 0) { Wbase = g_buf + U1X + (size_t)n * 8192; X = xx; }
            else           { if (t == 0) break; Wbase = g_buf + U1H + (size_t)n * 8192; X = xh; }
        } else {
            if (pass == 0) { if (t == 0) break; Wbase = g_buf + U0H + (size_t)n * 8192; X = xh; }
            else break;
        }
        for (int ch = 0; ch < 4; ch++) {
            __syncthreads();
            const float4* wsrc = (const float4*)(Wbase + ch * 2048);
            float4* wdst = (float4*)Wl;
            for (int idx = tid; idx < 512; idx += 256) wdst[idx] = wsrc[idx];
            __syncthreads();
            #pragma unroll 4
            for (int kq = 0; kq < 32; kq += 4) {
                float4 xv[8];
                #pragma unroll
                for (int j = 0; j < 8; j++) xv[j] = *(const float4*)&X[(bl0 + j) * 136 + ch * 32 + kq];
                #pragma unroll
                for (int q = 0; q < 4; q++) {
                    float w = Wl[(kq + q) * 64 + o];
                    #pragma unroll
                    for (int j = 0; j < 8; j++) acc[j] += ((const float*)&xv[j])[q] * w;
                }
            }
        }
    }
    size_t Hoff = lay ? OFF_H1 : OFF_H0;
    size_t Roff = lay ? OFF_R1 : OFF_R0;
    #pragma unroll
    for (int j = 0; j < 8; j++) {
        int b = bl0 + j;
        size_t base = (size_t)n * 2048 + (size_t)b * 64 + o;
        float hc = tanhf(acc[j]);
        float r = g_buf[Roff + base];
        float hold = g_buf[Hoff + base];
        float hn = r * hold + (1.f - r) * hc;
        g_buf[Hoff + base] = hn;
        if (!lay) g_buf[OFF_OUT0 + (pbase + b) * 64 + o] = hn;
    }
}

// ---------------- fused attention (t=T-1 only) + LN1; 4 (b,n) per block ----------------
__global__ __launch_bounds__(256) void k_attn() {
    int wid = threadIdx.x >> 6;
    int lane = threadIdx.x & 63;
    int g = blockIdx.x * 4 + wid;
    int b = g / NN, n = g - b * NN;
    __shared__ float x[4][TT][HH], kk[4][TT][HH], vv[4][TT][HH];
    __shared__ float q[4][HH], o1[4][HH], sc[4][HEADS][TT], aw[4][HEADS][TT];
    float mw = g_buf[S_MLW + lane];
    float mb = g_buf[S_MLB + lane];
    #pragma unroll
    for (int tt = 0; tt < TT; tt++) {
        float s = g_buf[S_SRC + ((size_t)b * TT + tt) * NN + n];
        x[wid][tt][lane] = s * mw + mb + g_buf[OFF_PE + tt * HH + lane];
    }
    __syncthreads();
    float ka[TT], va[TT];
    #pragma unroll
    for (int tt = 0; tt < TT; tt++) { ka[tt] = g_buf[S_BK + lane]; va[tt] = g_buf[S_BV + lane]; }
    float qa = g_buf[S_BQ + lane];
    for (int i = 0; i < HH; i++) {
        float wkv = g_buf[S_WK + i * HH + lane];
        float wvv = g_buf[S_WV + i * HH + lane];
        qa += x[wid][TT - 1][i] * g_buf[S_WQ + i * HH + lane];
        #pragma unroll
        for (int tt = 0; tt < TT; tt++) {
            float xv = x[wid][tt][i];
            ka[tt] += xv * wkv;
            va[tt] += xv * wvv;
        }
    }
    #pragma unroll
    for (int tt = 0; tt < TT; tt++) { kk[wid][tt][lane] = ka[tt]; vv[wid][tt][lane] = va[tt]; }
    q[wid][lane] = qa;
    __syncthreads();
    if (lane < HEADS * TT) {
        int head = lane / TT, ts = lane - head * TT;
        float s = 0.f;
        #pragma unroll
        for (int d = 0; d < HD; d++) s += q[wid][head * HD + d] * kk[wid][ts][head * HD + d];
        sc[wid][head][ts] = s * 0.25f;
    }
    __syncthreads();
    if (lane < HEADS * TT) {
        int head = lane / TT, ts = lane - head * TT;
        float mx = -1e30f;
        #pragma unroll
        for (int j = 0; j < TT; j++) mx = fmaxf(mx, sc[wid][head][j]);
        float sm = 0.f;
        #pragma unroll
        for (int j = 0; j < TT; j++) sm += expf(sc[wid][head][j] - mx);
        aw[wid][head][ts] = expf(sc[wid][head][ts] - mx) / sm;
    }
    __syncthreads();
    int head = lane >> 4;
    float oa = 0.f;
    #pragma unroll
    for (int tt = 0; tt < TT; tt++) oa += aw[wid][head][tt] * vv[wid][tt][lane];
    o1[wid][lane] = oa;
    __syncthreads();
    float acc = g_buf[S_BO + lane];
    for (int i = 0; i < HH; i++) acc += o1[wid][i] * g_buf[S_WO + i * HH + lane];
    float res = x[wid][TT - 1][lane] + acc;
    float mean = wave_sum(res) * (1.f / 64.f);
    float dv = res - mean;
    float var = wave_sum(dv * dv) * (1.f / 64.f);
    float ln = dv * rsqrtf(var + 1e-5f) * g_buf[S_L1G + lane] + g_buf[S_L1B + lane];
    g_buf[OFF_OLN + ((size_t)b * NN + n) * HH + lane] = ln;
}

// ---------------- FFN + LN2; 8 tokens per block ----------------
__global__ __launch_bounds__(256) void k_ffn() {
    int tok0 = blockIdx.x * 8;
    int tid = threadIdx.x;
    __shared__ float ox[8][HH];
    __shared__ float hid[8][1024];
    for (int idx = tid; idx < 8 * HH; idx += 256) {
        int tk = idx >> 6, hh = idx & 63;
        ox[tk][hh] = g_buf[OFF_OLN + (size_t)(tok0 + tk) * HH + hh];
    }
    __syncthreads();
    #pragma unroll
    for (int p = 0; p < 4; p++) {
        int j = tid + 256 * p;
        float bj = g_buf[S_FB1 + j];
        float a[8];
        #pragma unroll
        for (int tk = 0; tk < 8; tk++) a[tk] = bj;
        for (int i = 0; i < HH; i++) {
            float w = g_buf[S_FW1 + (size_t)i * 1024 + j];
            #pragma unroll
            for (int tk = 0; tk < 8; tk++) a[tk] += ox[tk][i] * w;
        }
        #pragma unroll
        for (int tk = 0; tk < 8; tk++) hid[tk][j] = fmaxf(a[tk], 0.f);
    }
    __syncthreads();
    int tk = tid >> 6, hh = tid & 63;
    float acc0 = g_buf[S_FB2 + hh], acc1 = acc0;
    for (int j = 0; j < 1024; j++) {
        float w = g_buf[S_FW2 + (size_t)j * HH + hh];
        acc0 += hid[tk][j] * w;
        acc1 += hid[tk + 4][j] * w;
    }
    #pragma unroll
    for (int ph = 0; ph < 2; ph++) {
        int tkk = tk + 4 * ph;
        float res = ox[tkk][hh] + (ph ? acc1 : acc0);
        float mean = wave_sum(res) * (1.f / 64.f);
        float dv = res - mean;
        float var = wave_sum(dv * dv) * (1.f / 64.f);
        float ln = dv * rsqrtf(var + 1e-5f) * g_buf[S_L2G + hh] + g_buf[S_L2B + hh];
        g_buf[OFF_O2 + (size_t)(tok0 + tkk) * HH + hh] = ln;
    }
}

// ---------------- final combine + horizon conv (layer-1 h is OFF_H1) ----------------
__global__ void k_final(void* out) {
    int n = blockIdx.x, b = blockIdx.y;
    int h = threadIdx.x;
    __shared__ float comb[HH];
    comb[h] = g_buf[OFF_H1 + ((size_t)n * 32 + b) * 64 + h] * g_buf[S_WS + n * HH + h]
            + g_buf[OFF_O2 + ((size_t)b * NN + n) * 64 + h] * g_buf[S_WT + n * HH + h];
    __syncthreads();
    if (h < HORIZON) {
        float acc = g_buf[S_CB + h];
        #pragma unroll
        for (int i = 0; i < HH; i++) acc += comb[i] * g_buf[S_CW + h * HH + i];
        size_t oi = ((size_t)b * HORIZON + h) * NN + n;
        if (g_flag) ((bf16*)out)[oi] = __float2bfloat16(acc);
        else        ((float*)out)[oi] = acc;
    }
}

extern "C" void kernel_launch(void* const* d_in, const int* in_sizes, int n_in,
                              void* d_out, int out_size, void* d_ws, size_t ws_size,
                              hipStream_t stream) {
    PtrPack pk;
    for (int i = 0; i < 32; i++) pk.p[i] = d_in[i];

    k_detect<<<1, 64, 0, stream>>>(d_in[1]);
    k_ingest<<<4133, 256, 0, stream>>>(pk);
    k_adj<<<NN, 512, 0, stream>>>();
    k_nodew_all<<<89337, 256, 0, stream>>>();
    k_pe<<<1, 768, 0, stream>>>();
    k_ax0<<<dim3(39, 12), 256, 0, stream>>>();
    k_xprep0<<<dim3(12, NN), 256, 0, stream>>>();
    k_zero<<<2456, 256, 0, stream>>>(OFF_H0, 628736);
    k_zero<<<2456, 256, 0, stream>>>(OFF_H1, 628736);

    // ---- pipelined supersteps: L0 t=s, L1 t=s-1 ----
    for (int s = 0; s <= TT; s++) {
        if (s >= 1)
            k_aggmat<<<dim3(5, 32), 256, 0, stream>>>(OFF_OUT0 + (size_t)(s - 1) * 628736,
                                                      OFF_AX1 + (size_t)(s - 1) * 628736);
        k_gateM<<<2 * NN, 256, 0, stream>>>(s);
        k_updM<<<2 * NN, 256, 0, stream>>>(s);
    }

    // ---- transformer branch ----
    k_attn<<<2456, 256, 0, stream>>>();
    k_ffn<<<1228, 256, 0, stream>>>();
    // ---- combine + conv ----
    k_final<<<dim3(NN, BB), 64, 0, stream>>>(d_out);
}

// Round 12
// 2716.364 us; speedup vs baseline: 1.9017x; 1.2105x over previous
//
#include <hip/hip_runtime.h>
#include <hip/hip_bf16.h>

typedef __hip_bfloat16 bf16;

constexpr int NN = 307, TT = 12, BB = 32, HH = 64, EE = 10, HEADS = 4, HD = 16, HORIZON = 12;

// ---------------- staged fp32 input offsets ----------------
constexpr int S_SRC = 0,       S_EMB = 117888,  S_GW0 = 120958,  S_GB0 = 287358,
              S_UW0 = 288638,  S_UB0 = 371838,  S_GW1 = 372478,  S_GB1 = 700158,
              S_UW1 = 701438,  S_UB1 = 865278,  S_MLW = 865918,  S_MLB = 865982,
              S_WQ  = 866046,  S_BQ  = 870142,  S_WK  = 870206,  S_BK  = 874302,
              S_WV  = 874366,  S_BV  = 878462,  S_WO  = 878526,  S_BO  = 882622,
              S_FW1 = 882686,  S_FB1 = 948222,  S_FW2 = 949246,  S_FB2 = 1014782,
              S_L1G = 1014846, S_L1B = 1014910, S_L2G = 1014974, S_L2B = 1015038,
              S_WS  = 1015102, S_WT  = 1034750, S_CW  = 1054398, S_CB  = 1055166;

// ---------------- fp32 work regions ----------------
constexpr size_t OFF_A    = 1055178;   // 307*307
constexpr size_t OFF_OUT0 = 1149427;   // [t][n][b][c] 12*307*2048
constexpr size_t OFF_H0   = 8694259;   // [n][b][c] 307*2048 (layer 0)
constexpr size_t OFF_ZH0  = 9322995;
constexpr size_t OFF_R0   = 9951731;
constexpr size_t OFF_AX0  = 11209203;  // [t][n][b] 12*307*32
constexpr size_t OFF_AX1  = 11327091;  // [t][n][b][c] 12*307*2048
constexpr size_t OFF_PE   = 18871923;  // 12*64
constexpr size_t OFF_OLN  = 18872691;
constexpr size_t OFF_O2   = 19501427;
constexpr size_t OFF_WB   = 20130164;  // fp32 reordered per-node GRU weights

// Reordered weight blocks (fp32; bf16 storage fails: scan amplifies to 0.19 absmax — r3)
constexpr size_t G0X = OFF_WB +        0;  // 307*2*128
constexpr size_t G0H = OFF_WB +    78592;  // 307*128*128
constexpr size_t BG0 = OFF_WB +  5108480;  // 307*128
constexpr size_t U0X = OFF_WB +  5147776;  // 307*2*64
constexpr size_t U0H = OFF_WB +  5187072;  // 307*128*64
constexpr size_t BU0 = OFF_WB +  7702016;  // 307*64
constexpr size_t G1X = OFF_WB +  7721664;  // 307*128*128
constexpr size_t G1H = OFF_WB + 12751552;  // 307*128*128
constexpr size_t BG1 = OFF_WB + 17781440;  // 307*128
constexpr size_t U1X = OFF_WB + 17820736;  // 307*128*64
constexpr size_t U1H = OFF_WB + 20335680;  // 307*128*64
constexpr size_t BU1 = OFF_WB + 22850624;  // 307*64
constexpr size_t OFF_GXP = OFF_WB + 22870272;       // [t][n][b][128] L0 preact x-part (bias folded)
constexpr size_t OFF_UXP = OFF_GXP + 15089664;      // [t][n][b][64]
constexpr size_t OFF_H1  = OFF_UXP + 7544832;       // layer-1 state buffers
constexpr size_t OFF_ZH1 = OFF_H1  + 628736;
constexpr size_t OFF_R1  = OFF_ZH1 + 628736;
constexpr size_t OFF_AGG0 = OFF_R1  + 628736;       // A@H (or A@ZH) per layer
constexpr size_t OFF_AGG1 = OFF_AGG0 + 628736;
constexpr size_t G_TOTAL  = OFF_AGG1 + 628736 + 4096;

// r11->r12: own-agg REMOVED from gateM/updM — it made every block read its layer's
// full 2.5MB state (1.5GB logical/dispatch -> gateM 110us, FETCH 70MB). Dedicated
// tiled agg GEMM has ~60x less traffic (~12.5MB/layer). Supersteps keep the lag-1
// L0/L1 merge; each superstep: aggB(H0,H1,AX1) -> gateM -> aggB(ZH0,ZH1) -> updM.
// 50 serial dispatches. Accumulation order unchanged (m ascending) -> same absmax.

__device__ float g_buf[G_TOTAL];
__device__ int g_flag;   // 1 = inputs are bf16, 0 = fp32

__device__ __forceinline__ float wave_sum(float v) {
    #pragma unroll
    for (int off = 32; off > 0; off >>= 1) v += __shfl_xor(v, off, 64);
    return v;
}

// ---------------- dtype detection ----------------
__global__ void k_detect(const void* emb_raw) {
    const bf16* p = (const bf16*)emb_raw;
    int lane = threadIdx.x;
    float v = __bfloat162float(p[lane]);
    bool plaus = (v == v) && (fabsf(v) <= 1e4f) && (v == 0.f || fabsf(v) >= 1e-4f);
    float c = wave_sum(plaus ? 1.f : 0.f);
    if (lane == 0) g_flag = (c >= 52.f) ? 1 : 0;
}

// ---------------- ingest all inputs as fp32 ----------------
struct PtrPack { const void* p[32]; };
__device__ const int D_CNT[32] = {117888,3070,166400,1280,83200,640,327680,1280,163840,640,
                                  64,64,4096,64,4096,64,4096,64,4096,64,
                                  65536,1024,65536,64,64,64,64,64,19648,19648,768,12};
__device__ const int D_OFF[32] = {S_SRC,S_EMB,S_GW0,S_GB0,S_UW0,S_UB0,S_GW1,S_GB1,S_UW1,S_UB1,
                                  S_MLW,S_MLB,S_WQ,S_BQ,S_WK,S_BK,S_WV,S_BV,S_WO,S_BO,
                                  S_FW1,S_FB1,S_FW2,S_FB2,S_L1G,S_L1B,S_L2G,S_L2B,S_WS,S_WT,S_CW,S_CB};
__device__ const int D_CHK[33] = {0,461,473,1123,1128,1453,1456,2736,2741,3381,3384,3385,3386,
                                  3402,3403,3419,3420,3436,3437,3453,3454,3710,3714,3970,3971,
                                  3972,3973,3974,3975,4052,4129,4132,4133};

__global__ void k_ingest(PtrPack pk) {
    int bid = blockIdx.x;
    int s = 0;
    while (s < 31 && bid >= D_CHK[s + 1]) s++;
    int i = (bid - D_CHK[s]) * 256 + threadIdx.x;
    if (i >= D_CNT[s]) return;
    float v;
    if (g_flag) v = __bfloat162float(((const bf16*)pk.p[s])[i]);
    else        v = ((const float*)pk.p[s])[i];
    g_buf[(size_t)D_OFF[s] + i] = v;
}

// ---------------- adjacency ----------------
__global__ void k_adj() {
    int n = blockIdx.x;
    int tid = threadIdx.x;            // 512
    __shared__ float en[EE];
    __shared__ float red[512];
    if (tid < EE) en[tid] = g_buf[S_EMB + n * EE + tid];
    __syncthreads();
    bool act = tid < NN;
    float d = 0.f;
    if (act) {
        #pragma unroll
        for (int e = 0; e < EE; e++) d += en[e] * g_buf[S_EMB + tid * EE + e];
        d = fmaxf(d, 0.f);
    }
    red[tid] = act ? d : -1e30f;
    __syncthreads();
    for (int s = 256; s > 0; s >>= 1) { if (tid < s) red[tid] = fmaxf(red[tid], red[tid + s]); __syncthreads(); }
    float mx = red[0];
    __syncthreads();
    float ex = act ? expf(d - mx) : 0.f;
    red[tid] = ex;
    __syncthreads();
    for (int s = 256; s > 0; s >>= 1) { if (tid < s) red[tid] += red[tid + s]; __syncthreads(); }
    float inv = 1.f / red[0];
    if (act) g_buf[OFF_A + (size_t)n * NN + tid] = ex * inv;
}

// ---------------- per-node GRU weights -> fp32, reordered into Wx/Wh blocks ----------------
__device__ const unsigned SEGC[9] = {0u,5108480u,5147776u,7702016u,7721664u,17781440u,17820736u,22850624u,22870272u};
__device__ const int SEGJ[8]      = {16640,128,8320,64,32768,128,16384,64};
__device__ const int SEGS[8]      = {S_GW0,S_GB0,S_UW0,S_UB0,S_GW1,S_GB1,S_UW1,S_UB1};

__global__ void k_nodew_all() {
    unsigned idx = blockIdx.x * 256u + threadIdx.x;
    if (idx >= 22870272u) return;
    int s = 0;
    while (s < 7 && idx >= SEGC[s + 1]) s++;
    unsigned rem = idx - SEGC[s];
    unsigned J = (unsigned)SEGJ[s];
    unsigned n = rem / J;
    unsigned j = rem - n * J;
    float acc = 0.f;
    const float* eb = g_buf + S_EMB + n * EE;
    const float* w  = g_buf + SEGS[s];
    #pragma unroll
    for (int e = 0; e < EE; e++) acc += eb[e] * w[(size_t)e * J + j];
    size_t dst;
    if (s == 0) {        // gw0: j = (k*65+i)*128+o
        unsigned o = j & 127, kk = j >> 7, k = kk / 65, i = kk % 65;
        dst = (i == 0) ? G0X + ((size_t)n * 2 + k) * 128 + o
                       : G0H + ((size_t)n * 128 + k * 64 + (i - 1)) * 128 + o;
    } else if (s == 1) { dst = BG0 + (size_t)n * 128 + j;
    } else if (s == 2) { // uw0: j = (k*65+i)*64+o
        unsigned o = j & 63, kk = j >> 6, k = kk / 65, i = kk % 65;
        dst = (i == 0) ? U0X + ((size_t)n * 2 + k) * 64 + o
                       : U0H + ((size_t)n * 128 + k * 64 + (i - 1)) * 64 + o;
    } else if (s == 3) { dst = BU0 + (size_t)n * 64 + j;
    } else if (s == 4) { // gw1: j = (k*128+i)*128+o
        unsigned o = j & 127, kk = j >> 7, k = kk >> 7, i = kk & 127;
        dst = (i < 64) ? G1X + ((size_t)n * 128 + k * 64 + i) * 128 + o
                       : G1H + ((size_t)n * 128 + k * 64 + (i - 64)) * 128 + o;
    } else if (s == 5) { dst = BG1 + (size_t)n * 128 + j;
    } else if (s == 6) { // uw1: j = (k*128+i)*64+o
        unsigned o = j & 63, kk = j >> 6, k = kk >> 7, i = kk & 127;
        dst = (i < 64) ? U1X + ((size_t)n * 128 + k * 64 + i) * 64 + o
                       : U1H + ((size_t)n * 128 + k * 64 + (i - 64)) * 64 + o;
    } else {             dst = BU1 + (size_t)n * 64 + j; }
    g_buf[dst] = acc;
}

// ---------------- positional embedding ----------------
__global__ void k_pe() {
    int tid = threadIdx.x;            // 768
    int t = tid >> 6, h = tid & 63;
    float ex = (float)(h & ~1) / 64.f;
    float ang = (float)t * powf(10000.f, -ex);
    g_buf[OFF_PE + tid] = (h & 1) ? cosf(ang) : sinf(ang);
}

__global__ void k_zero(size_t off, int cnt) {
    int i = blockIdx.x * 256 + threadIdx.x;
    if (i < cnt) g_buf[off + i] = 0.f;
}

// ---------------- AX0[t][n][b] = sum_m A[n,m] * src[b,t,m] ----------------
__global__ __launch_bounds__(256) void k_ax0() {
    int t = blockIdx.y;
    int n0 = blockIdx.x * 8;
    int b = threadIdx.x & 31, nl = threadIdx.x >> 5;
    __shared__ float As[8][68];
    __shared__ float xs[32][65];
    float acc = 0.f;
    for (int m0 = 0; m0 < NN; m0 += 64) {
        int jend = min(64, NN - m0);
        for (int idx = threadIdx.x; idx < 8 * 64; idx += 256) {
            int i = idx >> 6, jj = idx & 63;
            int n = n0 + i, m = m0 + jj;
            As[i][jj] = (n < NN && m < NN) ? g_buf[OFF_A + (size_t)n * NN + m] : 0.f;
        }
        for (int idx = threadIdx.x; idx < 32 * 64; idx += 256) {
            int bb = idx >> 6, jj = idx & 63;
            int m = m0 + jj;
            xs[bb][jj] = (m < NN) ? g_buf[S_SRC + ((size_t)bb * TT + t) * NN + m] : 0.f;
        }
        __syncthreads();
        for (int jj = 0; jj < jend; jj++) acc += As[nl][jj] * xs[b][jj];
        __syncthreads();
    }
    int n = n0 + nl;
    if (n < NN) g_buf[OFF_AX0 + ((size_t)t * NN + n) * 32 + b] = acc;
}

// ---------------- batched agg GEMM: z selects job ----------------
// mode 0 (z<3): H0->AGG0, H1->AGG1, OUT0[s-1]->AX1[s-1]
// mode 1 (z<2): ZH0->AGG0, ZH1->AGG1
__global__ __launch_bounds__(256) void k_aggB(int s, int mode) {
    int z = blockIdx.z;
    size_t srcOff, dstOff;
    if (mode == 0) {
        if (z == 0)      { srcOff = OFF_H0; dstOff = OFF_AGG0; }
        else if (z == 1) { srcOff = OFF_H1; dstOff = OFF_AGG1; }
        else             { srcOff = OFF_OUT0 + (size_t)(s - 1) * 628736;
                           dstOff = OFF_AX1  + (size_t)(s - 1) * 628736; }
    } else {
        srcOff = z ? OFF_ZH1 : OFF_ZH0;
        dstOff = z ? OFF_AGG1 : OFF_AGG0;
    }
    const float* __restrict__ srcp = g_buf + srcOff;
    float* __restrict__ dstp = g_buf + dstOff;
    int n0 = blockIdx.x * 64;
    int col0 = blockIdx.y * 64;
    int tid = threadIdx.x;
    int tn = tid >> 4, tc = tid & 15;
    __shared__ float As[32][68];
    __shared__ float Xs[32][64];
    float acc[4][4];
    #pragma unroll
    for (int i = 0; i < 4; i++)
        #pragma unroll
        for (int j = 0; j < 4; j++) acc[i][j] = 0.f;
    for (int k0 = 0; k0 < NN; k0 += 32) {
        for (int idx = tid; idx < 64 * 32; idx += 256) {
            int k = idx & 31, i = idx >> 5;
            int n = n0 + i, m = k0 + k;
            As[k][i] = (n < NN && m < NN) ? g_buf[OFF_A + (size_t)n * NN + m] : 0.f;
        }
        for (int idx = tid; idx < 32 * 64; idx += 256) {
            int c = idx & 63, k = idx >> 6;
            int m = k0 + k;
            Xs[k][c] = (m < NN) ? srcp[(size_t)m * 2048 + col0 + c] : 0.f;
        }
        __syncthreads();
        #pragma unroll
        for (int k = 0; k < 32; k++) {
            float4 a4 = *(const float4*)&As[k][tn * 4];
            float4 x4 = *(const float4*)&Xs[k][tc * 4];
            const float* aa = (const float*)&a4;
            const float* xx = (const float*)&x4;
            #pragma unroll
            for (int i = 0; i < 4; i++)
                #pragma unroll
                for (int j = 0; j < 4; j++) acc[i][j] += aa[i] * xx[j];
        }
        __syncthreads();
    }
    #pragma unroll
    for (int i = 0; i < 4; i++) {
        int n = n0 + tn * 4 + i;
        if (n < NN) {
            float4 v = make_float4(acc[i][0], acc[i][1], acc[i][2], acc[i][3]);
            *(float4*)&dstp[(size_t)n * 2048 + col0 + tc * 4] = v;
        }
    }
}

// ---------------- x-part preact precompute, layer 0 (K=2); grid (12, NN) ----------------
__global__ __launch_bounds__(256) void k_xprep0() {
    int t = blockIdx.x, n = blockIdx.y, tid = threadIdx.x;
    __shared__ float xv[32], ax[32];
    if (tid < 32) {
        xv[tid] = g_buf[S_SRC + ((size_t)tid * TT + t) * NN + n];
        ax[tid] = g_buf[OFF_AX0 + ((size_t)t * NN + n) * 32 + tid];
    }
    __syncthreads();
    size_t pbase = ((size_t)t * NN + n) * 32;
    for (int idx = tid; idx < 4096; idx += 256) {
        int b = idx >> 7, o = idx & 127;
        g_buf[OFF_GXP + (pbase + b) * 128 + o] =
            g_buf[BG0 + (size_t)n * 128 + o]
          + g_buf[G0X + ((size_t)n * 2 + 0) * 128 + o] * xv[b]
          + g_buf[G0X + ((size_t)n * 2 + 1) * 128 + o] * ax[b];
    }
    for (int idx = tid; idx < 2048; idx += 256) {
        int b = idx >> 6, o = idx & 63;
        g_buf[OFF_UXP + (pbase + b) * 64 + o] =
            g_buf[BU0 + (size_t)n * 64 + o]
          + g_buf[U0X + ((size_t)n * 2 + 0) * 64 + o] * xv[b]
          + g_buf[U0X + ((size_t)n * 2 + 1) * 64 + o] * ax[b];
    }
}

// ======== merged pipelined gate (no own-agg; reads AGG buffers) ========
// smem: xh 32*136 | xx 32*136 | Wl 32*128
__global__ __launch_bounds__(256) void k_gateM(int s) {
    __shared__ float smem[12800];
    float* xh = smem;
    float* xx = smem + 4352;
    float* Wl = smem + 8704;
    int lay = (blockIdx.x >= NN) ? 1 : 0;
    int n = blockIdx.x - lay * NN;
    int t = lay ? (s - 1) : s;
    if (t < 0 || t >= TT) return;
    int tid = threadIdx.x;
    size_t Hoff = lay ? OFF_H1 : OFF_H0;
    size_t Aoff = lay ? OFF_AGG1 : OFF_AGG0;
    for (int idx = tid; idx < 4096; idx += 256) {
        int bl = idx >> 7, c = idx & 127;
        float v = (c < 64) ? g_buf[Hoff + (size_t)n * 2048 + bl * 64 + c]
                           : g_buf[Aoff + (size_t)n * 2048 + bl * 64 + (c - 64)];
        xh[bl * 136 + c] = v;
    }
    if (lay) {
        size_t pb = ((size_t)t * NN + n) * 2048;
        for (int idx = tid; idx < 4096; idx += 256) {
            int bl = idx >> 7, c = idx & 127;
            float v = (c < 64) ? g_buf[OFF_OUT0 + pb + bl * 64 + c]
                               : g_buf[OFF_AX1 + pb + bl * 64 + (c - 64)];
            xx[bl * 136 + c] = v;
        }
    }
    __syncthreads();
    int o = tid & 63, bl0 = (tid >> 6) * 8;
    size_t pbase = ((size_t)t * NN + n) * 32;
    float accz[8], accr[8];
    if (lay) {
        #pragma unroll
        for (int j = 0; j < 8; j++) {
            accz[j] = g_buf[BG1 + (size_t)n * 128 + o];
            accr[j] = g_buf[BG1 + (size_t)n * 128 + o + 64];
        }
    } else {
        #pragma unroll
        for (int j = 0; j < 8; j++) {
            accz[j] = g_buf[OFF_GXP + (pbase + bl0 + j) * 128 + o];
            accr[j] = g_buf[OFF_GXP + (pbase + bl0 + j) * 128 + o + 64];
        }
    }
    for (int pass = 0; pass < 2; pass++) {
        const float* Wbase;
        const float* X;
        if (lay) {
            if (pass == 0) { Wbase = g_buf + G1X + (size_t)n * 16384; X = xx; }
            else           { if (t == 0) break; Wbase = g_buf + G1H + (size_t)n * 16384; X = xh; }
        } else {
            if (pass == 0) { if (t == 0) break; Wbase = g_buf + G0H + (size_t)n * 16384; X = xh; }
            else break;
        }
        for (int ch = 0; ch < 4; ch++) {
            __syncthreads();
            const float4* wsrc = (const float4*)(Wbase + ch * 4096);
            float4* wdst = (float4*)Wl;
            for (int idx = tid; idx < 1024; idx += 256) wdst[idx] = wsrc[idx];
            __syncthreads();
            #pragma unroll 4
            for (int kq = 0; kq < 32; kq += 4) {
                float4 xv[8];
                #pragma unroll
                for (int j = 0; j < 8; j++) xv[j] = *(const float4*)&X[(bl0 + j) * 136 + ch * 32 + kq];
                #pragma unroll
                for (int q = 0; q < 4; q++) {
                    float w0 = Wl[(kq + q) * 128 + o];
                    float w1 = Wl[(kq + q) * 128 + o + 64];
                    #pragma unroll
                    for (int j = 0; j < 8; j++) {
                        float xxv = ((const float*)&xv[j])[q];
                        accz[j] += xxv * w0;
                        accr[j] += xxv * w1;
                    }
                }
            }
        }
    }
    size_t ZHoff = lay ? OFF_ZH1 : OFF_ZH0;
    size_t Roff  = lay ? OFF_R1 : OFF_R0;
    #pragma unroll
    for (int j = 0; j < 8; j++) {
        int b = bl0 + j;
        float z = 1.f / (1.f + expf(-accz[j]));
        float r = 1.f / (1.f + expf(-accr[j]));
        float hv = xh[b * 136 + o];
        g_buf[ZHoff + (size_t)n * 2048 + (size_t)b * 64 + o] = z * hv;
        g_buf[Roff  + (size_t)n * 2048 + (size_t)b * 64 + o] = r;
    }
}

// ======== merged pipelined update (no own-agg) ========
__global__ __launch_bounds__(256) void k_updM(int s) {
    __shared__ float smem[10752];
    float* xh = smem;
    float* xx = smem + 4352;
    float* Wl = smem + 8704;   // 32*64
    int lay = (blockIdx.x >= NN) ? 1 : 0;
    int n = blockIdx.x - lay * NN;
    int t = lay ? (s - 1) : s;
    if (t < 0 || t >= TT) return;
    int tid = threadIdx.x;
    size_t ZHoff = lay ? OFF_ZH1 : OFF_ZH0;
    size_t Aoff  = lay ? OFF_AGG1 : OFF_AGG0;
    for (int idx = tid; idx < 4096; idx += 256) {
        int bl = idx >> 7, c = idx & 127;
        float v = (c < 64) ? g_buf[ZHoff + (size_t)n * 2048 + bl * 64 + c]
                           : g_buf[Aoff + (size_t)n * 2048 + bl * 64 + (c - 64)];
        xh[bl * 136 + c] = v;
    }
    if (lay) {
        size_t pb = ((size_t)t * NN + n) * 2048;
        for (int idx = tid; idx < 4096; idx += 256) {
            int bl = idx >> 7, c = idx & 127;
            float v = (c < 64) ? g_buf[OFF_OUT0 + pb + bl * 64 + c]
                               : g_buf[OFF_AX1 + pb + bl * 64 + (c - 64)];
            xx[bl * 136 + c] = v;
        }
    }
    __syncthreads();
    int o = tid & 63, bl0 = (tid >> 6) * 8;
    size_t pbase = ((size_t)t * NN + n) * 32;
    float acc[8];
    if (lay) {
        #pragma unroll
        for (int j = 0; j < 8; j++) acc[j] = g_buf[BU1 + (size_t)n * 64 + o];
    } else {
        #pragma unroll
        for (int j = 0; j < 8; j++) acc[j] = g_buf[OFF_UXP + (pbase + bl0 + j) * 64 + o];
    }
    for (int pass = 0; pass < 2; pass++) {
        const float* Wbase;
        const float* X;
        if (lay) {
            if (pass == 0) { Wbase = g_buf + U1X + (size_t)n * 8192; X = xx; }
            else           { if (t == 0) break; Wbase = g_buf + U1H + (size_t)n * 8192; X = xh; }
        } else {
            if (pass == 0) { if (t == 0) break; Wbase = g_buf + U0H + (size_t)n * 8192; X = xh; }
            else break;
        }
        for (int ch = 0; ch < 4; ch++) {
            __syncthreads();
            const float4* wsrc = (const float4*)(Wbase + ch * 2048);
            float4* wdst = (float4*)Wl;
            for (int idx = tid; idx < 512; idx += 256) wdst[idx] = wsrc[idx];
            __syncthreads();
            #pragma unroll 4
            for (int kq = 0; kq < 32; kq += 4) {
                float4 xv[8];
                #pragma unroll
                for (int j = 0; j < 8; j++) xv[j] = *(const float4*)&X[(bl0 + j) * 136 + ch * 32 + kq];
                #pragma unroll
                for (int q = 0; q < 4; q++) {
                    float w = Wl[(kq + q) * 64 + o];
                    #pragma unroll
                    for (int j = 0; j < 8; j++) acc[j] += ((const float*)&xv[j])[q] * w;
                }
            }
        }
    }
    size_t Hoff = lay ? OFF_H1 : OFF_H0;
    size_t Roff = lay ? OFF_R1 : OFF_R0;
    #pragma unroll
    for (int j = 0; j < 8; j++) {
        int b = bl0 + j;
        size_t base = (size_t)n * 2048 + (size_t)b * 64 + o;
        float hc = tanhf(acc[j]);
        float r = g_buf[Roff + base];
        float hold = g_buf[Hoff + base];
        float hn = r * hold + (1.f - r) * hc;
        g_buf[Hoff + base] = hn;
        if (!lay) g_buf[OFF_OUT0 + (pbase + b) * 64 + o] = hn;
    }
}

// ---------------- fused attention (t=T-1 only) + LN1; 4 (b,n) per block ----------------
__global__ __launch_bounds__(256) void k_attn() {
    int wid = threadIdx.x >> 6;
    int lane = threadIdx.x & 63;
    int g = blockIdx.x * 4 + wid;
    int b = g / NN, n = g - b * NN;
    __shared__ float x[4][TT][HH], kk[4][TT][HH], vv[4][TT][HH];
    __shared__ float q[4][HH], o1[4][HH], sc[4][HEADS][TT], aw[4][HEADS][TT];
    float mw = g_buf[S_MLW + lane];
    float mb = g_buf[S_MLB + lane];
    #pragma unroll
    for (int tt = 0; tt < TT; tt++) {
        float s = g_buf[S_SRC + ((size_t)b * TT + tt) * NN + n];
        x[wid][tt][lane] = s * mw + mb + g_buf[OFF_PE + tt * HH + lane];
    }
    __syncthreads();
    float ka[TT], va[TT];
    #pragma unroll
    for (int tt = 0; tt < TT; tt++) { ka[tt] = g_buf[S_BK + lane]; va[tt] = g_buf[S_BV + lane]; }
    float qa = g_buf[S_BQ + lane];
    for (int i = 0; i < HH; i++) {
        float wkv = g_buf[S_WK + i * HH + lane];
        float wvv = g_buf[S_WV + i * HH + lane];
        qa += x[wid][TT - 1][i] * g_buf[S_WQ + i * HH + lane];
        #pragma unroll
        for (int tt = 0; tt < TT; tt++) {
            float xv = x[wid][tt][i];
            ka[tt] += xv * wkv;
            va[tt] += xv * wvv;
        }
    }
    #pragma unroll
    for (int tt = 0; tt < TT; tt++) { kk[wid][tt][lane] = ka[tt]; vv[wid][tt][lane] = va[tt]; }
    q[wid][lane] = qa;
    __syncthreads();
    if (lane < HEADS * TT) {
        int head = lane / TT, ts = lane - head * TT;
        float s = 0.f;
        #pragma unroll
        for (int d = 0; d < HD; d++) s += q[wid][head * HD + d] * kk[wid][ts][head * HD + d];
        sc[wid][head][ts] = s * 0.25f;
    }
    __syncthreads();
    if (lane < HEADS * TT) {
        int head = lane / TT, ts = lane - head * TT;
        float mx = -1e30f;
        #pragma unroll
        for (int j = 0; j < TT; j++) mx = fmaxf(mx, sc[wid][head][j]);
        float sm = 0.f;
        #pragma unroll
        for (int j = 0; j < TT; j++) sm += expf(sc[wid][head][j] - mx);
        aw[wid][head][ts] = expf(sc[wid][head][ts] - mx) / sm;
    }
    __syncthreads();
    int head = lane >> 4;
    float oa = 0.f;
    #pragma unroll
    for (int tt = 0; tt < TT; tt++) oa += aw[wid][head][tt] * vv[wid][tt][lane];
    o1[wid][lane] = oa;
    __syncthreads();
    float acc = g_buf[S_BO + lane];
    for (int i = 0; i < HH; i++) acc += o1[wid][i] * g_buf[S_WO + i * HH + lane];
    float res = x[wid][TT - 1][lane] + acc;
    float mean = wave_sum(res) * (1.f / 64.f);
    float dv = res - mean;
    float var = wave_sum(dv * dv) * (1.f / 64.f);
    float ln = dv * rsqrtf(var + 1e-5f) * g_buf[S_L1G + lane] + g_buf[S_L1B + lane];
    g_buf[OFF_OLN + ((size_t)b * NN + n) * HH + lane] = ln;
}

// ---------------- FFN + LN2; 8 tokens per block ----------------
__global__ __launch_bounds__(256) void k_ffn() {
    int tok0 = blockIdx.x * 8;
    int tid = threadIdx.x;
    __shared__ float ox[8][HH];
    __shared__ float hid[8][1024];
    for (int idx = tid; idx < 8 * HH; idx += 256) {
        int tk = idx >> 6, hh = idx & 63;
        ox[tk][hh] = g_buf[OFF_OLN + (size_t)(tok0 + tk) * HH + hh];
    }
    __syncthreads();
    #pragma unroll
    for (int p = 0; p < 4; p++) {
        int j = tid + 256 * p;
        float bj = g_buf[S_FB1 + j];
        float a[8];
        #pragma unroll
        for (int tk = 0; tk < 8; tk++) a[tk] = bj;
        for (int i = 0; i < HH; i++) {
            float w = g_buf[S_FW1 + (size_t)i * 1024 + j];
            #pragma unroll
            for (int tk = 0; tk < 8; tk++) a[tk] += ox[tk][i] * w;
        }
        #pragma unroll
        for (int tk = 0; tk < 8; tk++) hid[tk][j] = fmaxf(a[tk], 0.f);
    }
    __syncthreads();
    int tk = tid >> 6, hh = tid & 63;
    float acc0 = g_buf[S_FB2 + hh], acc1 = acc0;
    for (int j = 0; j < 1024; j++) {
        float w = g_buf[S_FW2 + (size_t)j * HH + hh];
        acc0 += hid[tk][j] * w;
        acc1 += hid[tk + 4][j] * w;
    }
    #pragma unroll
    for (int ph = 0; ph < 2; ph++) {
        int tkk = tk + 4 * ph;
        float res = ox[tkk][hh] + (ph ? acc1 : acc0);
        float mean = wave_sum(res) * (1.f / 64.f);
        float dv = res - mean;
        float var = wave_sum(dv * dv) * (1.f / 64.f);
        float ln = dv * rsqrtf(var + 1e-5f) * g_buf[S_L2G + hh] + g_buf[S_L2B + hh];
        g_buf[OFF_O2 + (size_t)(tok0 + tkk) * HH + hh] = ln;
    }
}

// ---------------- final combine + horizon conv (layer-1 h is OFF_H1) ----------------
__global__ void k_final(void* out) {
    int n = blockIdx.x, b = blockIdx.y;
    int h = threadIdx.x;
    __shared__ float comb[HH];
    comb[h] = g_buf[OFF_H1 + ((size_t)n * 32 + b) * 64 + h] * g_buf[S_WS + n * HH + h]
            + g_buf[OFF_O2 + ((size_t)b * NN + n) * 64 + h] * g_buf[S_WT + n * HH + h];
    __syncthreads();
    if (h < HORIZON) {
        float acc = g_buf[S_CB + h];
        #pragma unroll
        for (int i = 0; i < HH; i++) acc += comb[i] * g_buf[S_CW + h * HH + i];
        size_t oi = ((size_t)b * HORIZON + h) * NN + n;
        if (g_flag) ((bf16*)out)[oi] = __float2bfloat16(acc);
        else        ((float*)out)[oi] = acc;
    }
}

extern "C" void kernel_launch(void* const* d_in, const int* in_sizes, int n_in,
                              void* d_out, int out_size, void* d_ws, size_t ws_size,
                              hipStream_t stream) {
    PtrPack pk;
    for (int i = 0; i < 32; i++) pk.p[i] = d_in[i];

    k_detect<<<1, 64, 0, stream>>>(d_in[1]);
    k_ingest<<<4133, 256, 0, stream>>>(pk);
    k_adj<<<NN, 512, 0, stream>>>();
    k_nodew_all<<<89337, 256, 0, stream>>>();
    k_pe<<<1, 768, 0, stream>>>();
    k_ax0<<<dim3(39, 12), 256, 0, stream>>>();
    k_xprep0<<<dim3(12, NN), 256, 0, stream>>>();
    k_zero<<<2456, 256, 0, stream>>>(OFF_H0, 628736);
    k_zero<<<2456, 256, 0, stream>>>(OFF_H1, 628736);

    // ---- pipelined supersteps: L0 t=s, L1 t=s-1 ----
    // s=0: H=0 -> no agg dispatches needed (gate/upd t==0 skip the agg-consuming passes)
    k_gateM<<<2 * NN, 256, 0, stream>>>(0);
    k_updM<<<2 * NN, 256, 0, stream>>>(0);
    for (int s = 1; s <= TT; s++) {
        k_aggB<<<dim3(5, 32, 3), 256, 0, stream>>>(s, 0);  // A@H0, A@H1, AX1[s-1]
        k_gateM<<<2 * NN, 256, 0, stream>>>(s);
        k_aggB<<<dim3(5, 32, 2), 256, 0, stream>>>(s, 1);  // A@ZH0, A@ZH1
        k_updM<<<2 * NN, 256, 0, stream>>>(s);
    }

    // ---- transformer branch ----
    k_attn<<<2456, 256, 0, stream>>>();
    k_ffn<<<1228, 256, 0, stream>>>();
    // ---- combine + conv ----
    k_final<<<dim3(NN, BB), 64, 0, stream>>>(d_out);
}